// Round 17
// baseline (164.507 us; speedup 1.0000x reference)
//
#include <hip/hip_runtime.h>
#include <hip/hip_bf16.h>
#include <math.h>

// ---------------------------------------------------------------------------
// Hybrid_QuanvModel — round 17: R16 conv4 re-grid with FIXED geometry
// (4 oc/thread: kg4 x ocq16 x i5 = 320 thr, oc0 = och*64 + ocq*4).
// Everything else = R15 (best passing: 163 µs).
// ---------------------------------------------------------------------------

__device__ __forceinline__ float2 cmul(float2 a, float2 b) {
    return make_float2(a.x * b.x - a.y * b.y, a.x * b.y + a.y * b.x);
}
__device__ __forceinline__ float2 cfma(float2 a, float2 b, float2 acc) {
    acc.x += a.x * b.x - a.y * b.y;
    acc.y += a.x * b.y + a.y * b.x;
    return acc;
}

// ---------------------------------------------------------------------------
// Build V[s][t] = U3[s][t] * (-i)^popcount(t)   (16x16 complex)
// ---------------------------------------------------------------------------
__global__ __launch_bounds__(256) void k_build_V(const float* __restrict__ qw,
                                                 float2* __restrict__ Vout) {
    __shared__ float2 rot[3][4][2][2];
    __shared__ float2 L[16][16];
    __shared__ float2 U[16][16];
    __shared__ float2 T[16][16];

    int tid = threadIdx.x;
    if (tid < 12) {
        int l = tid >> 2, q = tid & 3;
        float phi = qw[(l * 4 + q) * 3 + 0];
        float th  = qw[(l * 4 + q) * 3 + 1];
        float om  = qw[(l * 4 + q) * 3 + 2];
        float c, s;
        sincosf(0.5f * th, &s, &c);
        float sa, ca, sb, cb;
        sincosf(0.5f * (phi + om), &sa, &ca);
        sincosf(0.5f * (phi - om), &sb, &cb);
        rot[l][q][0][0] = make_float2( ca * c, -sa * c);
        rot[l][q][0][1] = make_float2(-cb * s, -sb * s);
        rot[l][q][1][0] = make_float2( cb * s, -sb * s);
        rot[l][q][1][1] = make_float2( ca * c,  sa * c);
    }
    int s = tid >> 4, t = tid & 15;
    U[s][t] = make_float2((s == t) ? 1.f : 0.f, 0.f);
    __syncthreads();

    for (int l = 0; l < 3; ++l) {
        int r = l + 1;
        int ss = s;
        for (int i = 3; i >= 0; --i) {
            int c_ = i, t_ = (i + r) & 3;
            if ((ss >> (3 - c_)) & 1) ss ^= 1 << (3 - t_);
        }
        float2 v = make_float2(1.f, 0.f);
        #pragma unroll
        for (int q = 0; q < 4; ++q) {
            int bs = (ss >> (3 - q)) & 1;
            int bt = (t  >> (3 - q)) & 1;
            v = cmul(v, rot[l][q][bs][bt]);
        }
        L[s][t] = v;
        __syncthreads();
        float2 acc = make_float2(0.f, 0.f);
        #pragma unroll
        for (int k = 0; k < 16; ++k) acc = cfma(L[s][k], U[k][t], acc);
        T[s][t] = acc;
        __syncthreads();
        U[s][t] = T[s][t];
        __syncthreads();
    }
    float2 acc = make_float2(0.f, 0.f);
    #pragma unroll
    for (int k = 0; k < 16; ++k) acc = cfma(U[s][k], U[k][t], acc);
    T[s][t] = acc;
    __syncthreads();
    acc = make_float2(0.f, 0.f);
    #pragma unroll
    for (int k = 0; k < 16; ++k) acc = cfma(T[s][k], U[k][t], acc);
    int pc = __popc(t) & 3;
    float2 v;
    if      (pc == 0) v = acc;
    else if (pc == 1) v = make_float2( acc.y, -acc.x);
    else if (pc == 2) v = make_float2(-acc.x, -acc.y);
    else              v = make_float2(-acc.y,  acc.x);
    Vout[s * 16 + t] = v;
}

// ---------------------------------------------------------------------------
// weight transpose: w3 (64,32,4,4) -> wt3[ic][tap][oc] (32,16,64)
//                   w4 (128,64,4,4) -> wt4[ic][tap][oc] (64,16,128)
// ---------------------------------------------------------------------------
__global__ __launch_bounds__(256) void k_wtrans(const float* __restrict__ w3,
                                                const float* __restrict__ w4,
                                                float* __restrict__ wt3,
                                                float* __restrict__ wt4) {
    int idx = blockIdx.x * 256 + threadIdx.x;
    if (idx < 32768) {
        int oc = idx & 63, tap = (idx >> 6) & 15, ic = idx >> 10;
        wt3[idx] = w3[oc * 512 + ic * 16 + tap];
    } else {
        int o = idx - 32768;
        int oc = o & 127, tap = (o >> 7) & 15, ic = o >> 11;
        wt4[o] = w4[oc * 1024 + ic * 16 + tap];
    }
}

// ---------------------------------------------------------------------------
// conv1 (1->1, 8x8, s2) + tanh, direct.
// ---------------------------------------------------------------------------
__global__ __launch_bounds__(256) void k_conv1d(const float* __restrict__ x,
                                                const float* __restrict__ w,
                                                const float* __restrict__ bias,
                                                float* __restrict__ y) {
    int idx = blockIdx.x * 256 + threadIdx.x;      // 8100*256 exact
    int j = idx % 90;
    int t = idx / 90;
    int i = t % 90;
    int b = t / 90;
    const float* xb = x + b * 34596 + (2 * i) * 186 + 2 * j;
    float acc = bias[0];
    #pragma unroll
    for (int u = 0; u < 8; ++u) {
        const float* rp = xb + u * 186;
        float2 p0 = *(const float2*)(rp + 0);
        float2 p1 = *(const float2*)(rp + 2);
        float2 p2 = *(const float2*)(rp + 4);
        float2 p3 = *(const float2*)(rp + 6);
        acc = fmaf(w[u * 8 + 0], p0.x, acc);
        acc = fmaf(w[u * 8 + 1], p0.y, acc);
        acc = fmaf(w[u * 8 + 2], p1.x, acc);
        acc = fmaf(w[u * 8 + 3], p1.y, acc);
        acc = fmaf(w[u * 8 + 4], p2.x, acc);
        acc = fmaf(w[u * 8 + 5], p2.y, acc);
        acc = fmaf(w[u * 8 + 6], p3.x, acc);
        acc = fmaf(w[u * 8 + 7], p3.y, acc);
    }
    y[idx] = tanhf(acc);
}

// ---------------------------------------------------------------------------
// fused maxpool(4,2)*pi/2 + quanv + relu: (256,90,90) -> (256,4,22,22)
// ---------------------------------------------------------------------------
__global__ __launch_bounds__(256) void k_quanvp(const float* __restrict__ y,
                                                const float2* __restrict__ Vg,
                                                float* __restrict__ o) {
    __shared__ float2 V[256];
    V[threadIdx.x] = Vg[threadIdx.x];
    __syncthreads();

    int idx = blockIdx.x * 256 + threadIdx.x;      // 484*256 = 256*22*22
    int j = idx % 22;
    int t = idx / 22;
    int i = t % 22;
    int b = t / 22;

    const float* yb = y + b * 8100 + (4 * i) * 90 + 4 * j;
    float ra[6], rb[6];
    #pragma unroll
    for (int r = 0; r < 6; ++r) {
        const float* rp = yb + r * 90;
        float2 p0 = *(const float2*)(rp);
        float2 p1 = *(const float2*)(rp + 2);
        float2 p2 = *(const float2*)(rp + 4);
        float m01 = fmaxf(p0.x, p0.y);
        float m23 = fmaxf(p1.x, p1.y);
        float m45 = fmaxf(p2.x, p2.y);
        ra[r] = fmaxf(m01, m23);
        rb[r] = fmaxf(m23, m45);
    }
    const float S = 1.57079632679489662f;
    float a0 = S * fmaxf(fmaxf(ra[0], ra[1]), fmaxf(ra[2], ra[3]));
    float a1 = S * fmaxf(fmaxf(rb[0], rb[1]), fmaxf(rb[2], rb[3]));
    float a2 = S * fmaxf(fmaxf(ra[2], ra[3]), fmaxf(ra[4], ra[5]));
    float a3 = S * fmaxf(fmaxf(rb[2], rb[3]), fmaxf(rb[4], rb[5]));

    float cs[4], sn[4];
    sincosf(0.5f * a0, &sn[0], &cs[0]);
    sincosf(0.5f * a1, &sn[1], &cs[1]);
    sincosf(0.5f * a2, &sn[2], &cs[2]);
    sincosf(0.5f * a3, &sn[3], &cs[3]);

    float c[16];
    #pragma unroll
    for (int tt = 0; tt < 16; ++tt) {
        c[tt] = ((tt & 8) ? sn[0] : cs[0]) * ((tt & 4) ? sn[1] : cs[1]) *
                ((tt & 2) ? sn[2] : cs[2]) * ((tt & 1) ? sn[3] : cs[3]);
    }

    float e0 = 0.f, e1 = 0.f, e2 = 0.f, e3 = 0.f;
    #pragma unroll
    for (int s = 0; s < 16; ++s) {
        float re = 0.f, im = 0.f;
        #pragma unroll
        for (int tt = 0; tt < 16; ++tt) {
            float2 v = V[s * 16 + tt];
            re = fmaf(v.x, c[tt], re);
            im = fmaf(v.y, c[tt], im);
        }
        float pr = re * re + im * im;
        e0 += (s & 8) ? -pr : pr;
        e1 += (s & 4) ? -pr : pr;
        e2 += (s & 2) ? -pr : pr;
        e3 += (s & 1) ? -pr : pr;
    }
    float* ob = o + b * (4 * 484) + i * 22 + j;
    ob[0]    = fmaxf(e0, 0.f);
    ob[484]  = fmaxf(e1, 0.f);
    ob[968]  = fmaxf(e2, 0.f);
    ob[1452] = fmaxf(e3, 0.f);
}

// ---------------------------------------------------------------------------
// conv2 (4->32, 4x4, s1) + relu, LDS tiled.
// ---------------------------------------------------------------------------
__global__ __launch_bounds__(640) void k_conv2t(const float* __restrict__ x,
                                                const float* __restrict__ w,
                                                const float* __restrict__ bias,
                                                float* __restrict__ y) {
    __shared__ float Xs[4 * 22 * 28];
    __shared__ float Ws[32 * 68];
    int b = blockIdx.x;
    int tid = threadIdx.x;

    const float* xb = x + b * 1936;
    for (int k = tid; k < 1936; k += 640) {
        int ic = k / 484, rem = k % 484;
        int r = rem / 22, c = rem % 22;
        Xs[ic * 616 + r * 28 + c] = xb[k];
    }
    for (int k = tid; k < 2048; k += 640) {
        Ws[(k >> 6) * 68 + (k & 63)] = w[k];
    }
    __syncthreads();

    if (tid < 608) {
        int oc = tid / 19, i = tid % 19;
        float acc[19];
        float bv = bias[oc];
        #pragma unroll
        for (int j = 0; j < 19; ++j) acc[j] = bv;
        const float* wr = &Ws[oc * 68];
        #pragma unroll
        for (int ic = 0; ic < 4; ++ic) {
            #pragma unroll
            for (int u = 0; u < 4; ++u) {
                const float* rp = &Xs[ic * 616 + (i + u) * 28];
                float xr[22];
                #pragma unroll
                for (int k = 0; k < 5; ++k)
                    *(float4*)&xr[4 * k] = *(const float4*)(rp + 4 * k);
                *(float2*)&xr[20] = *(const float2*)(rp + 20);
                float4 wv = *(const float4*)(wr + ic * 16 + u * 4);
                #pragma unroll
                for (int j = 0; j < 19; ++j) {
                    acc[j] = fmaf(wv.x, xr[j],     acc[j]);
                    acc[j] = fmaf(wv.y, xr[j + 1], acc[j]);
                    acc[j] = fmaf(wv.z, xr[j + 2], acc[j]);
                    acc[j] = fmaf(wv.w, xr[j + 3], acc[j]);
                }
            }
        }
        float* yp = y + b * 11552 + oc * 361 + i * 19;
        #pragma unroll
        for (int j = 0; j < 19; ++j) yp[j] = fmaxf(acc[j], 0.f);
    }
}

// maxpool 4x4 s1: (256,32,19,19) -> (256,32,16,16)
__global__ __launch_bounds__(256) void k_pool2(const float* __restrict__ x,
                                               float* __restrict__ y) {
    int idx = blockIdx.x * 256 + threadIdx.x;
    int j = idx % 16;
    int t = idx / 16;
    int i = t % 16;
    int c = t / 16;
    const float* xb = x + c * 361 + i * 19 + j;
    float m = -INFINITY;
    #pragma unroll
    for (int u = 0; u < 4; ++u)
        #pragma unroll
        for (int v = 0; v < 4; ++v)
            m = fmaxf(m, xb[u * 19 + v]);
    y[idx] = m;
}

// ---------------------------------------------------------------------------
// conv3 (32->64, 4x4, s1) + relu — 4 oc/thread, K-split-4, rolled k-loop.
// grid = 512, block 448 = kg(4) x ocq(16) x il(7).  (R15, unchanged)
// ---------------------------------------------------------------------------
__global__ __launch_bounds__(448) void k_conv3y(const float* __restrict__ x,
                                                const float* __restrict__ wt3,
                                                const float* __restrict__ bias,
                                                float* __restrict__ y) {
    __shared__ float Xs[32 * 200];     // 25.6 KB
    __shared__ float Rs[112 * 57];     // 25.5 KB (stride 57: conflict-free)
    int bid = blockIdx.x;
    int b = bid >> 1, h = bid & 1;
    int r0 = h * 7;
    int nr = 7 - h;
    int tid = threadIdx.x;

    const float* xb = x + b * 8192 + r0 * 16;
    #pragma unroll
    for (int it = 0; it < 3; ++it) {
        int k = it * 448 + tid;
        if (k < 1280) {
            int ic = k / 40, rem = k % 40;
            int r = rem >> 2, c4 = rem & 3;
            if (r0 + r < 16) {
                float4 v = *(const float4*)(xb + ic * 256 + r * 16 + c4 * 4);
                *(float4*)(&Xs[ic * 200 + r * 20 + c4 * 4]) = v;
            }
        }
    }
    __syncthreads();

    int kg = tid / 112;                // 0..3 -> ic group
    int t2 = tid - kg * 112;
    int ocq = t2 & 15, il = t2 >> 4;   // il 0..6
    int oc0 = ocq * 4;

    float acc[4][13];
    #pragma unroll
    for (int o = 0; o < 4; ++o)
        #pragma unroll
        for (int j = 0; j < 13; ++j) acc[o][j] = 0.f;

    const float* wb = wt3 + kg * 8192 + oc0;   // 8 ics of 1024 floats
    #pragma unroll 1
    for (int k = 0; k < 8; ++k) {
        const float* wp = wb + k * 1024;
        const float* xc = &Xs[(kg * 8 + k) * 200 + il * 20];
        #pragma unroll
        for (int u = 0; u < 4; ++u) {
            float xr[16];
            const float* rp = xc + u * 20;
            #pragma unroll
            for (int kk = 0; kk < 4; ++kk)
                *(float4*)&xr[4 * kk] = *(const float4*)(rp + 4 * kk);
            #pragma unroll
            for (int v = 0; v < 4; ++v) {
                float4 wv = *(const float4*)(wp + (u * 4 + v) * 64);
                #pragma unroll
                for (int j = 0; j < 13; ++j) {
                    acc[0][j] = fmaf(wv.x, xr[j + v], acc[0][j]);
                    acc[1][j] = fmaf(wv.y, xr[j + v], acc[1][j]);
                    acc[2][j] = fmaf(wv.z, xr[j + v], acc[2][j]);
                    acc[3][j] = fmaf(wv.w, xr[j + v], acc[3][j]);
                }
            }
        }
    }

    // 3-phase sequential reduce into kg==0
    #pragma unroll
    for (int g = 1; g < 4; ++g) {
        __syncthreads();
        if (kg == g) {
            float* rp = &Rs[t2 * 57];
            #pragma unroll
            for (int o = 0; o < 4; ++o)
                #pragma unroll
                for (int j = 0; j < 13; ++j) rp[o * 13 + j] = acc[o][j];
        }
        __syncthreads();
        if (kg == 0) {
            const float* rp = &Rs[t2 * 57];
            #pragma unroll
            for (int o = 0; o < 4; ++o)
                #pragma unroll
                for (int j = 0; j < 13; ++j)
                    acc[o][j] += rp[o * 13 + j];
        }
    }

    if (kg == 0 && il < nr) {
        float* yp = y + b * 10816 + oc0 * 169 + (r0 + il) * 13;
        #pragma unroll
        for (int o = 0; o < 4; ++o) {
            float bv = bias[oc0 + o];
            #pragma unroll
            for (int j = 0; j < 13; ++j)
                yp[o * 169 + j] = fmaxf(acc[o][j] + bv, 0.f);
        }
    }
}

// ---------------------------------------------------------------------------
// conv4 (64->128, 4x4, s2) partials — 4 independent small blocks/CU.
// grid = 1024 = img(256) x kq(2) x ocHalf(2); block 320 = kg(4) x ocq(16) x i(5).
// 4 oc/thread: oc0 = och*64 + ocq*4 (64 oc per half-block, disjoint).
// pool3 fused into staging; rolled k-loop; 3-phase LDS reduce.
// ---------------------------------------------------------------------------
__global__ __launch_bounds__(320) void k_conv4q(const float* __restrict__ x3,
                                                const float* __restrict__ wt4,
                                                float* __restrict__ part) {
    __shared__ float Xs[32 * 144];     // 18.4 KB (kq half, pooled)
    __shared__ float Rs[80 * 21];      // 6.7 KB
    int bid = blockIdx.x;              // b*4 + kq*2 + och
    int b   = bid >> 2;
    int kq  = (bid >> 1) & 1;
    int och = bid & 1;
    int tid = threadIdx.x;

    // stage 32 channels of pooled (12x12) from conv3 output (13x13)
    const float* gb = x3 + b * 10816 + kq * 32 * 169;
    for (int k = tid; k < 4608; k += 320) {
        int ic = k / 144, rc = k % 144;
        int r = rc / 12, c = rc % 12;
        const float* g = gb + ic * 169 + r * 13 + c;
        Xs[k] = fmaxf(fmaxf(g[0], g[1]), fmaxf(g[13], g[14]));
    }
    __syncthreads();

    int kg = tid / 80;                 // 0..3 -> ic subgroup (8 ic each)
    int t2 = tid - kg * 80;
    int ocq = t2 / 5, i = t2 % 5;      // ocq 0..15, i 0..4
    int oc0 = och * 64 + ocq * 4;      // 4 oc/thread, 64 oc per half

    float acc[4][5];
    #pragma unroll
    for (int o = 0; o < 4; ++o)
        #pragma unroll
        for (int j = 0; j < 5; ++j) acc[o][j] = 0.f;

    const float* wb = wt4 + (kq * 32 + kg * 8) * 2048 + oc0;
    #pragma unroll 1
    for (int k = 0; k < 8; ++k) {
        const float* wp = wb + k * 2048;
        const float* xc = &Xs[(kg * 8 + k) * 144];
        #pragma unroll
        for (int u = 0; u < 4; ++u) {
            const float* rp = xc + (2 * i + u) * 12;
            float xr[12];
            #pragma unroll
            for (int kk = 0; kk < 3; ++kk)
                *(float4*)&xr[4 * kk] = *(const float4*)(rp + 4 * kk);
            #pragma unroll
            for (int v = 0; v < 4; ++v) {
                float4 wv = *(const float4*)(wp + (u * 4 + v) * 128);
                #pragma unroll
                for (int j = 0; j < 5; ++j) {
                    float xv = xr[2 * j + v];
                    acc[0][j] = fmaf(wv.x, xv, acc[0][j]);
                    acc[1][j] = fmaf(wv.y, xv, acc[1][j]);
                    acc[2][j] = fmaf(wv.z, xv, acc[2][j]);
                    acc[3][j] = fmaf(wv.w, xv, acc[3][j]);
                }
            }
        }
    }

    // 3-phase sequential reduce into kg==0
    #pragma unroll
    for (int g = 1; g < 4; ++g) {
        __syncthreads();
        if (kg == g) {
            float* rp = &Rs[t2 * 21];
            #pragma unroll
            for (int o = 0; o < 4; ++o)
                #pragma unroll
                for (int j = 0; j < 5; ++j) rp[o * 5 + j] = acc[o][j];
        }
        __syncthreads();
        if (kg == 0) {
            const float* rp = &Rs[t2 * 21];
            #pragma unroll
            for (int o = 0; o < 4; ++o)
                #pragma unroll
                for (int j = 0; j < 5; ++j) acc[o][j] += rp[o * 5 + j];
        }
    }

    if (kg == 0) {
        float* pp = part + kq * 819200 + b * 3200 + oc0 * 25 + i * 5;
        #pragma unroll
        for (int o = 0; o < 4; ++o)
            #pragma unroll
            for (int j = 0; j < 5; ++j) pp[o * 25 + j] = acc[o][j];
    }
}

// reduce 2 K-partials + bias + relu
__global__ __launch_bounds__(256) void k_c4red(const float* __restrict__ part,
                                               const float* __restrict__ bias,
                                               float* __restrict__ y) {
    int idx = blockIdx.x * 256 + threadIdx.x;       // 819200 exact
    float s = part[idx] + part[idx + 819200];
    int oc = (idx / 25) & 127;
    y[idx] = fmaxf(s + bias[oc], 0.f);
}

// ---------------------------------------------------------------------------
// fc1: (256,3200) @ (128,3200)^T + relu.
// ---------------------------------------------------------------------------
__global__ __launch_bounds__(256) void k_fc1t(const float* __restrict__ x,
                                              const float* __restrict__ w,
                                              const float* __restrict__ bias,
                                              float* __restrict__ y) {
    __shared__ float Ls[4][32][65];
    int bid = blockIdx.x;
    int ig = bid >> 2, ocg = bid & 3;
    int imgB = ig * 4, ocB = ocg * 32;
    int tid = threadIdx.x, lane = tid & 63, wv = tid >> 6;
    int ocW = ocB + wv * 8;

    float acc[8][4];
    #pragma unroll
    for (int o = 0; o < 8; ++o)
        #pragma unroll
        for (int m = 0; m < 4; ++m) acc[o][m] = 0.f;

    for (int it = 0; it < 25; ++it) {
        int k = it * 128 + lane * 2;
        float2 xv[4];
        #pragma unroll
        for (int m = 0; m < 4; ++m)
            xv[m] = *(const float2*)&x[(imgB + m) * 3200 + k];
        #pragma unroll
        for (int o = 0; o < 8; ++o) {
            float2 wvv = *(const float2*)&w[(ocW + o) * 3200 + k];
            #pragma unroll
            for (int m = 0; m < 4; ++m) {
                acc[o][m] = fmaf(wvv.x, xv[m].x, acc[o][m]);
                acc[o][m] = fmaf(wvv.y, xv[m].y, acc[o][m]);
            }
        }
    }
    #pragma unroll
    for (int o = 0; o < 8; ++o)
        #pragma unroll
        for (int m = 0; m < 4; ++m)
            Ls[wv][o * 4 + m][lane] = acc[o][m];
    __syncthreads();

    if (tid < 128) {
        int w2 = tid >> 5, r = tid & 31;
        const float* p = Ls[w2][r];
        float s = 0.f;
        #pragma unroll
        for (int c = 0; c < 64; ++c) s += p[c];
        int o = r >> 2, m = r & 3;
        int oc = ocB + w2 * 8 + o;
        y[(imgB + m) * 128 + oc] = fmaxf(s + bias[oc], 0.f);
    }
}

// ---------------------------------------------------------------------------
// fused fc2+relu, fc3+relu, fc4+log_softmax.
// ---------------------------------------------------------------------------
__global__ __launch_bounds__(64) void k_fc_tail(const float* __restrict__ x,
                                                const float* __restrict__ w2,
                                                const float* __restrict__ b2,
                                                const float* __restrict__ w3,
                                                const float* __restrict__ b3,
                                                const float* __restrict__ w4,
                                                const float* __restrict__ b4,
                                                float* __restrict__ out) {
    __shared__ float xs[128], h2[64], h3[16];
    int img = blockIdx.x;
    int lane = threadIdx.x;

    *(float2*)&xs[lane * 2] = *(const float2*)&x[img * 128 + lane * 2];
    __syncthreads();

    float a = b2[lane];
    const float4* wp = (const float4*)&w2[lane * 128];
    const float4* xp = (const float4*)xs;
    #pragma unroll
    for (int k = 0; k < 32; ++k) {
        float4 wv = wp[k], xv = xp[k];
        a = fmaf(wv.x, xv.x, a);
        a = fmaf(wv.y, xv.y, a);
        a = fmaf(wv.z, xv.z, a);
        a = fmaf(wv.w, xv.w, a);
    }
    h2[lane] = fmaxf(a, 0.f);
    __syncthreads();

    if (lane < 16) {
        float a3 = b3[lane];
        const float4* w3p = (const float4*)&w3[lane * 64];
        const float4* h2p = (const float4*)h2;
        #pragma unroll
        for (int k = 0; k < 16; ++k) {
            float4 wv = w3p[k], xv = h2p[k];
            a3 = fmaf(wv.x, xv.x, a3);
            a3 = fmaf(wv.y, xv.y, a3);
            a3 = fmaf(wv.z, xv.z, a3);
            a3 = fmaf(wv.w, xv.w, a3);
        }
        h3[lane] = fmaxf(a3, 0.f);
    }
    __syncthreads();

    if (lane == 0) {
        float z0 = b4[0], z1 = b4[1];
        #pragma unroll
        for (int k = 0; k < 16; ++k) {
            z0 = fmaf(w4[k],      h3[k], z0);
            z1 = fmaf(w4[16 + k], h3[k], z1);
        }
        float m = fmaxf(z0, z1);
        float lse = m + logf(expf(z0 - m) + expf(z1 - m));
        out[img * 2 + 0] = z0 - lse;
        out[img * 2 + 1] = z1 - lse;
    }
}

// ---------------------------------------------------------------------------
extern "C" void kernel_launch(void* const* d_in, const int* in_sizes, int n_in,
                              void* d_out, int out_size, void* d_ws, size_t ws_size,
                              hipStream_t stream) {
    const float* x       = (const float*)d_in[0];
    const float* conv1_w = (const float*)d_in[1];
    const float* conv1_b = (const float*)d_in[2];
    const float* q_w     = (const float*)d_in[3];
    const float* conv2_w = (const float*)d_in[4];
    const float* conv2_b = (const float*)d_in[5];
    const float* conv3_w = (const float*)d_in[6];
    const float* conv3_b = (const float*)d_in[7];
    const float* conv4_w = (const float*)d_in[8];
    const float* conv4_b = (const float*)d_in[9];
    const float* fc1_w   = (const float*)d_in[10];
    const float* fc1_b   = (const float*)d_in[11];
    const float* fc2_w   = (const float*)d_in[12];
    const float* fc2_b   = (const float*)d_in[13];
    const float* fc3_w   = (const float*)d_in[14];
    const float* fc3_b   = (const float*)d_in[15];
    const float* fc4_w   = (const float*)d_in[16];
    const float* fc4_b   = (const float*)d_in[17];
    float* out = (float*)d_out;

    char* ws = (char*)d_ws;
    float2* V  = (float2*)ws;                          // 2 KB
    float* A   = (float*)(ws + 4096);                  // 12 MB region
    float* B   = (float*)(ws + 12587008);              // 8.5 MB region
    float* WT3 = (float*)(ws + 21499904);              // 128 KB
    float* WT4 = (float*)(ws + 21639168);              // 512 KB

    k_build_V<<<1, 256, 0, stream>>>(q_w, V);
    k_wtrans<<<640, 256, 0, stream>>>(conv3_w, conv4_w, WT3, WT4);
    k_conv1d<<<8100, 256, 0, stream>>>(x, conv1_w, conv1_b, A);
    k_quanvp<<<484, 256, 0, stream>>>(A, V, B);
    k_conv2t<<<256, 640, 0, stream>>>(B, conv2_w, conv2_b, A);
    k_pool2<<<8192, 256, 0, stream>>>(A, B);
    k_conv3y<<<512, 448, 0, stream>>>(B, WT3, conv3_b, A);
    k_conv4q<<<1024, 320, 0, stream>>>(A, WT4, B);
    k_c4red<<<3200, 256, 0, stream>>>(B, conv4_b, A);
    k_fc1t<<<256, 256, 0, stream>>>(A, fc1_w, fc1_b, B);
    k_fc_tail<<<256, 64, 0, stream>>>(B, fc2_w, fc2_b, fc3_w, fc3_b,
                                      fc4_w, fc4_b, out);
}

// Round 18
// 162.008 us; speedup vs baseline: 1.0154x; 1.0154x over previous
//
#include <hip/hip_runtime.h>
#include <hip/hip_bf16.h>
#include <math.h>

// ---------------------------------------------------------------------------
// Hybrid_QuanvModel — round 18: R15 config (best: 163 µs) + c4red fused
// into fc1 (k_fc1f reads conv4 K-partials directly, bias+relu inline).
// ---------------------------------------------------------------------------

__device__ __forceinline__ float2 cmul(float2 a, float2 b) {
    return make_float2(a.x * b.x - a.y * b.y, a.x * b.y + a.y * b.x);
}
__device__ __forceinline__ float2 cfma(float2 a, float2 b, float2 acc) {
    acc.x += a.x * b.x - a.y * b.y;
    acc.y += a.x * b.y + a.y * b.x;
    return acc;
}

// ---------------------------------------------------------------------------
// Build V[s][t] = U3[s][t] * (-i)^popcount(t)   (16x16 complex)
// ---------------------------------------------------------------------------
__global__ __launch_bounds__(256) void k_build_V(const float* __restrict__ qw,
                                                 float2* __restrict__ Vout) {
    __shared__ float2 rot[3][4][2][2];
    __shared__ float2 L[16][16];
    __shared__ float2 U[16][16];
    __shared__ float2 T[16][16];

    int tid = threadIdx.x;
    if (tid < 12) {
        int l = tid >> 2, q = tid & 3;
        float phi = qw[(l * 4 + q) * 3 + 0];
        float th  = qw[(l * 4 + q) * 3 + 1];
        float om  = qw[(l * 4 + q) * 3 + 2];
        float c, s;
        sincosf(0.5f * th, &s, &c);
        float sa, ca, sb, cb;
        sincosf(0.5f * (phi + om), &sa, &ca);
        sincosf(0.5f * (phi - om), &sb, &cb);
        rot[l][q][0][0] = make_float2( ca * c, -sa * c);
        rot[l][q][0][1] = make_float2(-cb * s, -sb * s);
        rot[l][q][1][0] = make_float2( cb * s, -sb * s);
        rot[l][q][1][1] = make_float2( ca * c,  sa * c);
    }
    int s = tid >> 4, t = tid & 15;
    U[s][t] = make_float2((s == t) ? 1.f : 0.f, 0.f);
    __syncthreads();

    for (int l = 0; l < 3; ++l) {
        int r = l + 1;
        int ss = s;
        for (int i = 3; i >= 0; --i) {
            int c_ = i, t_ = (i + r) & 3;
            if ((ss >> (3 - c_)) & 1) ss ^= 1 << (3 - t_);
        }
        float2 v = make_float2(1.f, 0.f);
        #pragma unroll
        for (int q = 0; q < 4; ++q) {
            int bs = (ss >> (3 - q)) & 1;
            int bt = (t  >> (3 - q)) & 1;
            v = cmul(v, rot[l][q][bs][bt]);
        }
        L[s][t] = v;
        __syncthreads();
        float2 acc = make_float2(0.f, 0.f);
        #pragma unroll
        for (int k = 0; k < 16; ++k) acc = cfma(L[s][k], U[k][t], acc);
        T[s][t] = acc;
        __syncthreads();
        U[s][t] = T[s][t];
        __syncthreads();
    }
    float2 acc = make_float2(0.f, 0.f);
    #pragma unroll
    for (int k = 0; k < 16; ++k) acc = cfma(U[s][k], U[k][t], acc);
    T[s][t] = acc;
    __syncthreads();
    acc = make_float2(0.f, 0.f);
    #pragma unroll
    for (int k = 0; k < 16; ++k) acc = cfma(T[s][k], U[k][t], acc);
    int pc = __popc(t) & 3;
    float2 v;
    if      (pc == 0) v = acc;
    else if (pc == 1) v = make_float2( acc.y, -acc.x);
    else if (pc == 2) v = make_float2(-acc.x, -acc.y);
    else              v = make_float2(-acc.y,  acc.x);
    Vout[s * 16 + t] = v;
}

// ---------------------------------------------------------------------------
// weight transpose: w3 (64,32,4,4) -> wt3[ic][tap][oc] (32,16,64)
//                   w4 (128,64,4,4) -> wt4[ic][tap][oc] (64,16,128)
// ---------------------------------------------------------------------------
__global__ __launch_bounds__(256) void k_wtrans(const float* __restrict__ w3,
                                                const float* __restrict__ w4,
                                                float* __restrict__ wt3,
                                                float* __restrict__ wt4) {
    int idx = blockIdx.x * 256 + threadIdx.x;
    if (idx < 32768) {
        int oc = idx & 63, tap = (idx >> 6) & 15, ic = idx >> 10;
        wt3[idx] = w3[oc * 512 + ic * 16 + tap];
    } else {
        int o = idx - 32768;
        int oc = o & 127, tap = (o >> 7) & 15, ic = o >> 11;
        wt4[o] = w4[oc * 1024 + ic * 16 + tap];
    }
}

// ---------------------------------------------------------------------------
// conv1 (1->1, 8x8, s2) + tanh, direct.
// ---------------------------------------------------------------------------
__global__ __launch_bounds__(256) void k_conv1d(const float* __restrict__ x,
                                                const float* __restrict__ w,
                                                const float* __restrict__ bias,
                                                float* __restrict__ y) {
    int idx = blockIdx.x * 256 + threadIdx.x;      // 8100*256 exact
    int j = idx % 90;
    int t = idx / 90;
    int i = t % 90;
    int b = t / 90;
    const float* xb = x + b * 34596 + (2 * i) * 186 + 2 * j;
    float acc = bias[0];
    #pragma unroll
    for (int u = 0; u < 8; ++u) {
        const float* rp = xb + u * 186;
        float2 p0 = *(const float2*)(rp + 0);
        float2 p1 = *(const float2*)(rp + 2);
        float2 p2 = *(const float2*)(rp + 4);
        float2 p3 = *(const float2*)(rp + 6);
        acc = fmaf(w[u * 8 + 0], p0.x, acc);
        acc = fmaf(w[u * 8 + 1], p0.y, acc);
        acc = fmaf(w[u * 8 + 2], p1.x, acc);
        acc = fmaf(w[u * 8 + 3], p1.y, acc);
        acc = fmaf(w[u * 8 + 4], p2.x, acc);
        acc = fmaf(w[u * 8 + 5], p2.y, acc);
        acc = fmaf(w[u * 8 + 6], p3.x, acc);
        acc = fmaf(w[u * 8 + 7], p3.y, acc);
    }
    y[idx] = tanhf(acc);
}

// ---------------------------------------------------------------------------
// fused maxpool(4,2)*pi/2 + quanv + relu: (256,90,90) -> (256,4,22,22)
// ---------------------------------------------------------------------------
__global__ __launch_bounds__(256) void k_quanvp(const float* __restrict__ y,
                                                const float2* __restrict__ Vg,
                                                float* __restrict__ o) {
    __shared__ float2 V[256];
    V[threadIdx.x] = Vg[threadIdx.x];
    __syncthreads();

    int idx = blockIdx.x * 256 + threadIdx.x;      // 484*256 = 256*22*22
    int j = idx % 22;
    int t = idx / 22;
    int i = t % 22;
    int b = t / 22;

    const float* yb = y + b * 8100 + (4 * i) * 90 + 4 * j;
    float ra[6], rb[6];
    #pragma unroll
    for (int r = 0; r < 6; ++r) {
        const float* rp = yb + r * 90;
        float2 p0 = *(const float2*)(rp);
        float2 p1 = *(const float2*)(rp + 2);
        float2 p2 = *(const float2*)(rp + 4);
        float m01 = fmaxf(p0.x, p0.y);
        float m23 = fmaxf(p1.x, p1.y);
        float m45 = fmaxf(p2.x, p2.y);
        ra[r] = fmaxf(m01, m23);
        rb[r] = fmaxf(m23, m45);
    }
    const float S = 1.57079632679489662f;
    float a0 = S * fmaxf(fmaxf(ra[0], ra[1]), fmaxf(ra[2], ra[3]));
    float a1 = S * fmaxf(fmaxf(rb[0], rb[1]), fmaxf(rb[2], rb[3]));
    float a2 = S * fmaxf(fmaxf(ra[2], ra[3]), fmaxf(ra[4], ra[5]));
    float a3 = S * fmaxf(fmaxf(rb[2], rb[3]), fmaxf(rb[4], rb[5]));

    float cs[4], sn[4];
    sincosf(0.5f * a0, &sn[0], &cs[0]);
    sincosf(0.5f * a1, &sn[1], &cs[1]);
    sincosf(0.5f * a2, &sn[2], &cs[2]);
    sincosf(0.5f * a3, &sn[3], &cs[3]);

    float c[16];
    #pragma unroll
    for (int tt = 0; tt < 16; ++tt) {
        c[tt] = ((tt & 8) ? sn[0] : cs[0]) * ((tt & 4) ? sn[1] : cs[1]) *
                ((tt & 2) ? sn[2] : cs[2]) * ((tt & 1) ? sn[3] : cs[3]);
    }

    float e0 = 0.f, e1 = 0.f, e2 = 0.f, e3 = 0.f;
    #pragma unroll
    for (int s = 0; s < 16; ++s) {
        float re = 0.f, im = 0.f;
        #pragma unroll
        for (int tt = 0; tt < 16; ++tt) {
            float2 v = V[s * 16 + tt];
            re = fmaf(v.x, c[tt], re);
            im = fmaf(v.y, c[tt], im);
        }
        float pr = re * re + im * im;
        e0 += (s & 8) ? -pr : pr;
        e1 += (s & 4) ? -pr : pr;
        e2 += (s & 2) ? -pr : pr;
        e3 += (s & 1) ? -pr : pr;
    }
    float* ob = o + b * (4 * 484) + i * 22 + j;
    ob[0]    = fmaxf(e0, 0.f);
    ob[484]  = fmaxf(e1, 0.f);
    ob[968]  = fmaxf(e2, 0.f);
    ob[1452] = fmaxf(e3, 0.f);
}

// ---------------------------------------------------------------------------
// conv2 (4->32, 4x4, s1) + relu, LDS tiled.
// ---------------------------------------------------------------------------
__global__ __launch_bounds__(640) void k_conv2t(const float* __restrict__ x,
                                                const float* __restrict__ w,
                                                const float* __restrict__ bias,
                                                float* __restrict__ y) {
    __shared__ float Xs[4 * 22 * 28];
    __shared__ float Ws[32 * 68];
    int b = blockIdx.x;
    int tid = threadIdx.x;

    const float* xb = x + b * 1936;
    for (int k = tid; k < 1936; k += 640) {
        int ic = k / 484, rem = k % 484;
        int r = rem / 22, c = rem % 22;
        Xs[ic * 616 + r * 28 + c] = xb[k];
    }
    for (int k = tid; k < 2048; k += 640) {
        Ws[(k >> 6) * 68 + (k & 63)] = w[k];
    }
    __syncthreads();

    if (tid < 608) {
        int oc = tid / 19, i = tid % 19;
        float acc[19];
        float bv = bias[oc];
        #pragma unroll
        for (int j = 0; j < 19; ++j) acc[j] = bv;
        const float* wr = &Ws[oc * 68];
        #pragma unroll
        for (int ic = 0; ic < 4; ++ic) {
            #pragma unroll
            for (int u = 0; u < 4; ++u) {
                const float* rp = &Xs[ic * 616 + (i + u) * 28];
                float xr[22];
                #pragma unroll
                for (int k = 0; k < 5; ++k)
                    *(float4*)&xr[4 * k] = *(const float4*)(rp + 4 * k);
                *(float2*)&xr[20] = *(const float2*)(rp + 20);
                float4 wv = *(const float4*)(wr + ic * 16 + u * 4);
                #pragma unroll
                for (int j = 0; j < 19; ++j) {
                    acc[j] = fmaf(wv.x, xr[j],     acc[j]);
                    acc[j] = fmaf(wv.y, xr[j + 1], acc[j]);
                    acc[j] = fmaf(wv.z, xr[j + 2], acc[j]);
                    acc[j] = fmaf(wv.w, xr[j + 3], acc[j]);
                }
            }
        }
        float* yp = y + b * 11552 + oc * 361 + i * 19;
        #pragma unroll
        for (int j = 0; j < 19; ++j) yp[j] = fmaxf(acc[j], 0.f);
    }
}

// maxpool 4x4 s1: (256,32,19,19) -> (256,32,16,16)
__global__ __launch_bounds__(256) void k_pool2(const float* __restrict__ x,
                                               float* __restrict__ y) {
    int idx = blockIdx.x * 256 + threadIdx.x;
    int j = idx % 16;
    int t = idx / 16;
    int i = t % 16;
    int c = t / 16;
    const float* xb = x + c * 361 + i * 19 + j;
    float m = -INFINITY;
    #pragma unroll
    for (int u = 0; u < 4; ++u)
        #pragma unroll
        for (int v = 0; v < 4; ++v)
            m = fmaxf(m, xb[u * 19 + v]);
    y[idx] = m;
}

// ---------------------------------------------------------------------------
// conv3 (32->64, 4x4, s1) + relu — 4 oc/thread, K-split-4, rolled k-loop.
// grid = 512, block 448 = kg(4) x ocq(16) x il(7).  (R15, unchanged)
// ---------------------------------------------------------------------------
__global__ __launch_bounds__(448) void k_conv3y(const float* __restrict__ x,
                                                const float* __restrict__ wt3,
                                                const float* __restrict__ bias,
                                                float* __restrict__ y) {
    __shared__ float Xs[32 * 200];     // 25.6 KB
    __shared__ float Rs[112 * 57];     // 25.5 KB (stride 57: conflict-free)
    int bid = blockIdx.x;
    int b = bid >> 1, h = bid & 1;
    int r0 = h * 7;
    int nr = 7 - h;
    int tid = threadIdx.x;

    const float* xb = x + b * 8192 + r0 * 16;
    #pragma unroll
    for (int it = 0; it < 3; ++it) {
        int k = it * 448 + tid;
        if (k < 1280) {
            int ic = k / 40, rem = k % 40;
            int r = rem >> 2, c4 = rem & 3;
            if (r0 + r < 16) {
                float4 v = *(const float4*)(xb + ic * 256 + r * 16 + c4 * 4);
                *(float4*)(&Xs[ic * 200 + r * 20 + c4 * 4]) = v;
            }
        }
    }
    __syncthreads();

    int kg = tid / 112;                // 0..3 -> ic group
    int t2 = tid - kg * 112;
    int ocq = t2 & 15, il = t2 >> 4;   // il 0..6
    int oc0 = ocq * 4;

    float acc[4][13];
    #pragma unroll
    for (int o = 0; o < 4; ++o)
        #pragma unroll
        for (int j = 0; j < 13; ++j) acc[o][j] = 0.f;

    const float* wb = wt3 + kg * 8192 + oc0;   // 8 ics of 1024 floats
    #pragma unroll 1
    for (int k = 0; k < 8; ++k) {
        const float* wp = wb + k * 1024;
        const float* xc = &Xs[(kg * 8 + k) * 200 + il * 20];
        #pragma unroll
        for (int u = 0; u < 4; ++u) {
            float xr[16];
            const float* rp = xc + u * 20;
            #pragma unroll
            for (int kk = 0; kk < 4; ++kk)
                *(float4*)&xr[4 * kk] = *(const float4*)(rp + 4 * kk);
            #pragma unroll
            for (int v = 0; v < 4; ++v) {
                float4 wv = *(const float4*)(wp + (u * 4 + v) * 64);
                #pragma unroll
                for (int j = 0; j < 13; ++j) {
                    acc[0][j] = fmaf(wv.x, xr[j + v], acc[0][j]);
                    acc[1][j] = fmaf(wv.y, xr[j + v], acc[1][j]);
                    acc[2][j] = fmaf(wv.z, xr[j + v], acc[2][j]);
                    acc[3][j] = fmaf(wv.w, xr[j + v], acc[3][j]);
                }
            }
        }
    }

    // 3-phase sequential reduce into kg==0
    #pragma unroll
    for (int g = 1; g < 4; ++g) {
        __syncthreads();
        if (kg == g) {
            float* rp = &Rs[t2 * 57];
            #pragma unroll
            for (int o = 0; o < 4; ++o)
                #pragma unroll
                for (int j = 0; j < 13; ++j) rp[o * 13 + j] = acc[o][j];
        }
        __syncthreads();
        if (kg == 0) {
            const float* rp = &Rs[t2 * 57];
            #pragma unroll
            for (int o = 0; o < 4; ++o)
                #pragma unroll
                for (int j = 0; j < 13; ++j)
                    acc[o][j] += rp[o * 13 + j];
        }
    }

    if (kg == 0 && il < nr) {
        float* yp = y + b * 10816 + oc0 * 169 + (r0 + il) * 13;
        #pragma unroll
        for (int o = 0; o < 4; ++o) {
            float bv = bias[oc0 + o];
            #pragma unroll
            for (int j = 0; j < 13; ++j)
                yp[o * 169 + j] = fmaxf(acc[o][j] + bv, 0.f);
        }
    }
}

// ---------------------------------------------------------------------------
// conv4 (64->128, 4x4, s2) partials — 4 oc/thread, K-split-4, rolled k-loop,
// pool3 fused into staging.  grid = 512, block 640 = kg(4) x ocq(32) x i(5).
// (R15 conv4y, best measured)
// ---------------------------------------------------------------------------
__global__ __launch_bounds__(640) void k_conv4y(const float* __restrict__ x3,
                                                const float* __restrict__ wt4,
                                                float* __restrict__ part) {
    __shared__ float Xs[32 * 144];     // 18.4 KB
    __shared__ float Rs[160 * 21];     // 13.4 KB
    int bid = blockIdx.x;
    int b = bid >> 1, kq = bid & 1;
    int tid = threadIdx.x;

    // stage 32 channels of pooled (12x12) from conv3 output (13x13)
    const float* gb = x3 + b * 10816 + kq * 32 * 169;
    for (int k = tid; k < 4608; k += 640) {
        int ic = k / 144, rc = k % 144;
        int r = rc / 12, c = rc % 12;
        const float* g = gb + ic * 169 + r * 13 + c;
        Xs[k] = fmaxf(fmaxf(g[0], g[1]), fmaxf(g[13], g[14]));
    }
    __syncthreads();

    int kg = tid / 160;                // 0..3
    int t2 = tid - kg * 160;
    int ocq = t2 & 31, i = t2 >> 5;    // i 0..4
    int oc0 = ocq * 4;

    float acc[4][5];
    #pragma unroll
    for (int o = 0; o < 4; ++o)
        #pragma unroll
        for (int j = 0; j < 5; ++j) acc[o][j] = 0.f;

    const float* wb = wt4 + (kq * 32 + kg * 8) * 2048 + oc0;
    #pragma unroll 1
    for (int k = 0; k < 8; ++k) {
        const float* wp = wb + k * 2048;
        const float* xc = &Xs[(kg * 8 + k) * 144];
        #pragma unroll
        for (int u = 0; u < 4; ++u) {
            const float* rp = xc + (2 * i + u) * 12;
            float xr[12];
            #pragma unroll
            for (int kk = 0; kk < 3; ++kk)
                *(float4*)&xr[4 * kk] = *(const float4*)(rp + 4 * kk);
            #pragma unroll
            for (int v = 0; v < 4; ++v) {
                float4 wv = *(const float4*)(wp + (u * 4 + v) * 128);
                #pragma unroll
                for (int j = 0; j < 5; ++j) {
                    float xv = xr[2 * j + v];
                    acc[0][j] = fmaf(wv.x, xv, acc[0][j]);
                    acc[1][j] = fmaf(wv.y, xv, acc[1][j]);
                    acc[2][j] = fmaf(wv.z, xv, acc[2][j]);
                    acc[3][j] = fmaf(wv.w, xv, acc[3][j]);
                }
            }
        }
    }

    #pragma unroll
    for (int g = 1; g < 4; ++g) {
        __syncthreads();
        if (kg == g) {
            float* rp = &Rs[t2 * 21];
            #pragma unroll
            for (int o = 0; o < 4; ++o)
                #pragma unroll
                for (int j = 0; j < 5; ++j) rp[o * 5 + j] = acc[o][j];
        }
        __syncthreads();
        if (kg == 0) {
            const float* rp = &Rs[t2 * 21];
            #pragma unroll
            for (int o = 0; o < 4; ++o)
                #pragma unroll
                for (int j = 0; j < 5; ++j) acc[o][j] += rp[o * 5 + j];
        }
    }

    if (kg == 0) {
        float* pp = part + kq * 819200 + b * 3200 + oc0 * 25 + i * 5;
        #pragma unroll
        for (int o = 0; o < 4; ++o)
            #pragma unroll
            for (int j = 0; j < 5; ++j) pp[o * 25 + j] = acc[o][j];
    }
}

// ---------------------------------------------------------------------------
// fc1 fused with c4red: x[img][k] = relu(part0[k] + part1[k] + b4[k/25]).
// (256,3200) @ (128,3200)^T + relu.
// ---------------------------------------------------------------------------
__global__ __launch_bounds__(256) void k_fc1f(const float* __restrict__ part,
                                              const float* __restrict__ w,
                                              const float* __restrict__ b4,
                                              const float* __restrict__ bias,
                                              float* __restrict__ y) {
    __shared__ float Ls[4][32][65];
    int bid = blockIdx.x;
    int ig = bid >> 2, ocg = bid & 3;
    int imgB = ig * 4, ocB = ocg * 32;
    int tid = threadIdx.x, lane = tid & 63, wv = tid >> 6;
    int ocW = ocB + wv * 8;

    float acc[8][4];
    #pragma unroll
    for (int o = 0; o < 8; ++o)
        #pragma unroll
        for (int m = 0; m < 4; ++m) acc[o][m] = 0.f;

    for (int it = 0; it < 25; ++it) {
        int k = it * 128 + lane * 2;
        float ba = b4[k / 25];
        float bb = b4[(k + 1) / 25];
        float2 xv[4];
        #pragma unroll
        for (int m = 0; m < 4; ++m) {
            int base = (imgB + m) * 3200 + k;
            float2 p0 = *(const float2*)&part[base];
            float2 p1 = *(const float2*)&part[base + 819200];
            xv[m].x = fmaxf(p0.x + p1.x + ba, 0.f);
            xv[m].y = fmaxf(p0.y + p1.y + bb, 0.f);
        }
        #pragma unroll
        for (int o = 0; o < 8; ++o) {
            float2 wvv = *(const float2*)&w[(ocW + o) * 3200 + k];
            #pragma unroll
            for (int m = 0; m < 4; ++m) {
                acc[o][m] = fmaf(wvv.x, xv[m].x, acc[o][m]);
                acc[o][m] = fmaf(wvv.y, xv[m].y, acc[o][m]);
            }
        }
    }
    #pragma unroll
    for (int o = 0; o < 8; ++o)
        #pragma unroll
        for (int m = 0; m < 4; ++m)
            Ls[wv][o * 4 + m][lane] = acc[o][m];
    __syncthreads();

    if (tid < 128) {
        int w2 = tid >> 5, r = tid & 31;
        const float* p = Ls[w2][r];
        float s = 0.f;
        #pragma unroll
        for (int c = 0; c < 64; ++c) s += p[c];
        int o = r >> 2, m = r & 3;
        int oc = ocB + w2 * 8 + o;
        y[(imgB + m) * 128 + oc] = fmaxf(s + bias[oc], 0.f);
    }
}

// ---------------------------------------------------------------------------
// fused fc2+relu, fc3+relu, fc4+log_softmax.
// ---------------------------------------------------------------------------
__global__ __launch_bounds__(64) void k_fc_tail(const float* __restrict__ x,
                                                const float* __restrict__ w2,
                                                const float* __restrict__ b2,
                                                const float* __restrict__ w3,
                                                const float* __restrict__ b3,
                                                const float* __restrict__ w4,
                                                const float* __restrict__ b4,
                                                float* __restrict__ out) {
    __shared__ float xs[128], h2[64], h3[16];
    int img = blockIdx.x;
    int lane = threadIdx.x;

    *(float2*)&xs[lane * 2] = *(const float2*)&x[img * 128 + lane * 2];
    __syncthreads();

    float a = b2[lane];
    const float4* wp = (const float4*)&w2[lane * 128];
    const float4* xp = (const float4*)xs;
    #pragma unroll
    for (int k = 0; k < 32; ++k) {
        float4 wv = wp[k], xv = xp[k];
        a = fmaf(wv.x, xv.x, a);
        a = fmaf(wv.y, xv.y, a);
        a = fmaf(wv.z, xv.z, a);
        a = fmaf(wv.w, xv.w, a);
    }
    h2[lane] = fmaxf(a, 0.f);
    __syncthreads();

    if (lane < 16) {
        float a3 = b3[lane];
        const float4* w3p = (const float4*)&w3[lane * 64];
        const float4* h2p = (const float4*)h2;
        #pragma unroll
        for (int k = 0; k < 16; ++k) {
            float4 wv = w3p[k], xv = h2p[k];
            a3 = fmaf(wv.x, xv.x, a3);
            a3 = fmaf(wv.y, xv.y, a3);
            a3 = fmaf(wv.z, xv.z, a3);
            a3 = fmaf(wv.w, xv.w, a3);
        }
        h3[lane] = fmaxf(a3, 0.f);
    }
    __syncthreads();

    if (lane == 0) {
        float z0 = b4[0], z1 = b4[1];
        #pragma unroll
        for (int k = 0; k < 16; ++k) {
            z0 = fmaf(w4[k],      h3[k], z0);
            z1 = fmaf(w4[16 + k], h3[k], z1);
        }
        float m = fmaxf(z0, z1);
        float lse = m + logf(expf(z0 - m) + expf(z1 - m));
        out[img * 2 + 0] = z0 - lse;
        out[img * 2 + 1] = z1 - lse;
    }
}

// ---------------------------------------------------------------------------
extern "C" void kernel_launch(void* const* d_in, const int* in_sizes, int n_in,
                              void* d_out, int out_size, void* d_ws, size_t ws_size,
                              hipStream_t stream) {
    const float* x       = (const float*)d_in[0];
    const float* conv1_w = (const float*)d_in[1];
    const float* conv1_b = (const float*)d_in[2];
    const float* q_w     = (const float*)d_in[3];
    const float* conv2_w = (const float*)d_in[4];
    const float* conv2_b = (const float*)d_in[5];
    const float* conv3_w = (const float*)d_in[6];
    const float* conv3_b = (const float*)d_in[7];
    const float* conv4_w = (const float*)d_in[8];
    const float* conv4_b = (const float*)d_in[9];
    const float* fc1_w   = (const float*)d_in[10];
    const float* fc1_b   = (const float*)d_in[11];
    const float* fc2_w   = (const float*)d_in[12];
    const float* fc2_b   = (const float*)d_in[13];
    const float* fc3_w   = (const float*)d_in[14];
    const float* fc3_b   = (const float*)d_in[15];
    const float* fc4_w   = (const float*)d_in[16];
    const float* fc4_b   = (const float*)d_in[17];
    float* out = (float*)d_out;

    char* ws = (char*)d_ws;
    float2* V  = (float2*)ws;                          // 2 KB
    float* A   = (float*)(ws + 4096);                  // 12 MB region
    float* B   = (float*)(ws + 12587008);              // 8.5 MB region
    float* WT3 = (float*)(ws + 21499904);              // 128 KB
    float* WT4 = (float*)(ws + 21639168);              // 512 KB

    k_build_V<<<1, 256, 0, stream>>>(q_w, V);
    k_wtrans<<<640, 256, 0, stream>>>(conv3_w, conv4_w, WT3, WT4);
    k_conv1d<<<8100, 256, 0, stream>>>(x, conv1_w, conv1_b, A);
    k_quanvp<<<484, 256, 0, stream>>>(A, V, B);
    k_conv2t<<<256, 640, 0, stream>>>(B, conv2_w, conv2_b, A);
    k_pool2<<<8192, 256, 0, stream>>>(A, B);
    k_conv3y<<<512, 448, 0, stream>>>(B, WT3, conv3_b, A);
    k_conv4y<<<512, 640, 0, stream>>>(A, WT4, B);
    k_fc1f<<<256, 256, 0, stream>>>(B, fc1_w, conv4_b, fc1_b, A);
    k_fc_tail<<<256, 64, 0, stream>>>(A, fc2_w, fc2_b, fc3_w, fc3_b,
                                      fc4_w, fc4_b, out);
}

// Round 19
// 159.344 us; speedup vs baseline: 1.0324x; 1.0167x over previous
//
#include <hip/hip_runtime.h>
#include <hip/hip_bf16.h>
#include <math.h>

// ---------------------------------------------------------------------------
// Hybrid_QuanvModel — round 19: conv1 fused into quanv (k_cq: 8x18 rolling
// register window, bit-identical math).  9 launches.  Rest = R18 (162 µs).
// ---------------------------------------------------------------------------

__device__ __forceinline__ float2 cmul(float2 a, float2 b) {
    return make_float2(a.x * b.x - a.y * b.y, a.x * b.y + a.y * b.x);
}
__device__ __forceinline__ float2 cfma(float2 a, float2 b, float2 acc) {
    acc.x += a.x * b.x - a.y * b.y;
    acc.y += a.x * b.y + a.y * b.x;
    return acc;
}

// ---------------------------------------------------------------------------
// Build V[s][t] = U3[s][t] * (-i)^popcount(t)   (16x16 complex)
// ---------------------------------------------------------------------------
__global__ __launch_bounds__(256) void k_build_V(const float* __restrict__ qw,
                                                 float2* __restrict__ Vout) {
    __shared__ float2 rot[3][4][2][2];
    __shared__ float2 L[16][16];
    __shared__ float2 U[16][16];
    __shared__ float2 T[16][16];

    int tid = threadIdx.x;
    if (tid < 12) {
        int l = tid >> 2, q = tid & 3;
        float phi = qw[(l * 4 + q) * 3 + 0];
        float th  = qw[(l * 4 + q) * 3 + 1];
        float om  = qw[(l * 4 + q) * 3 + 2];
        float c, s;
        sincosf(0.5f * th, &s, &c);
        float sa, ca, sb, cb;
        sincosf(0.5f * (phi + om), &sa, &ca);
        sincosf(0.5f * (phi - om), &sb, &cb);
        rot[l][q][0][0] = make_float2( ca * c, -sa * c);
        rot[l][q][0][1] = make_float2(-cb * s, -sb * s);
        rot[l][q][1][0] = make_float2( cb * s, -sb * s);
        rot[l][q][1][1] = make_float2( ca * c,  sa * c);
    }
    int s = tid >> 4, t = tid & 15;
    U[s][t] = make_float2((s == t) ? 1.f : 0.f, 0.f);
    __syncthreads();

    for (int l = 0; l < 3; ++l) {
        int r = l + 1;
        int ss = s;
        for (int i = 3; i >= 0; --i) {
            int c_ = i, t_ = (i + r) & 3;
            if ((ss >> (3 - c_)) & 1) ss ^= 1 << (3 - t_);
        }
        float2 v = make_float2(1.f, 0.f);
        #pragma unroll
        for (int q = 0; q < 4; ++q) {
            int bs = (ss >> (3 - q)) & 1;
            int bt = (t  >> (3 - q)) & 1;
            v = cmul(v, rot[l][q][bs][bt]);
        }
        L[s][t] = v;
        __syncthreads();
        float2 acc = make_float2(0.f, 0.f);
        #pragma unroll
        for (int k = 0; k < 16; ++k) acc = cfma(L[s][k], U[k][t], acc);
        T[s][t] = acc;
        __syncthreads();
        U[s][t] = T[s][t];
        __syncthreads();
    }
    float2 acc = make_float2(0.f, 0.f);
    #pragma unroll
    for (int k = 0; k < 16; ++k) acc = cfma(U[s][k], U[k][t], acc);
    T[s][t] = acc;
    __syncthreads();
    acc = make_float2(0.f, 0.f);
    #pragma unroll
    for (int k = 0; k < 16; ++k) acc = cfma(T[s][k], U[k][t], acc);
    int pc = __popc(t) & 3;
    float2 v;
    if      (pc == 0) v = acc;
    else if (pc == 1) v = make_float2( acc.y, -acc.x);
    else if (pc == 2) v = make_float2(-acc.x, -acc.y);
    else              v = make_float2(-acc.y,  acc.x);
    Vout[s * 16 + t] = v;
}

// ---------------------------------------------------------------------------
// weight transpose: w3 (64,32,4,4) -> wt3[ic][tap][oc] (32,16,64)
//                   w4 (128,64,4,4) -> wt4[ic][tap][oc] (64,16,128)
// ---------------------------------------------------------------------------
__global__ __launch_bounds__(256) void k_wtrans(const float* __restrict__ w3,
                                                const float* __restrict__ w4,
                                                float* __restrict__ wt3,
                                                float* __restrict__ wt4) {
    int idx = blockIdx.x * 256 + threadIdx.x;
    if (idx < 32768) {
        int oc = idx & 63, tap = (idx >> 6) & 15, ic = idx >> 10;
        wt3[idx] = w3[oc * 512 + ic * 16 + tap];
    } else {
        int o = idx - 32768;
        int oc = o & 127, tap = (o >> 7) & 15, ic = o >> 11;
        wt4[o] = w4[oc * 1024 + ic * 16 + tap];
    }
}

// ---------------------------------------------------------------------------
// fused conv1(8x8,s2)+tanh + maxpool(4,2)*pi/2 + quanv + relu:
// x:(256,186,186) -> o:(256,4,22,22).  Thread = one 2x2 patch of pooled
// angles; computes its 6x6 conv1-out window from an 8x18 rolling register
// window (circular row slots, fully unrolled).  Math identical to the
// previous conv1d + quanvp pair.
// ---------------------------------------------------------------------------
__global__ __launch_bounds__(256) void k_cq(const float* __restrict__ x,
                                            const float* __restrict__ w,
                                            const float* __restrict__ bias,
                                            const float2* __restrict__ Vg,
                                            float* __restrict__ o) {
    __shared__ float2 V[256];
    V[threadIdx.x] = Vg[threadIdx.x];
    __syncthreads();

    int idx = blockIdx.x * 256 + threadIdx.x;      // 484*256 = 256*22*22
    int j = idx % 22;
    int t = idx / 22;
    int i = t % 22;
    int b = t / 22;

    const float* xb = x + b * 34596 + (8 * i) * 186 + 8 * j;
    float bv = bias[0];

    float win[8][18];
    #pragma unroll
    for (int u = 0; u < 8; ++u)
        #pragma unroll
        for (int k2 = 0; k2 < 9; ++k2)
            *(float2*)&win[u][2 * k2] = *(const float2*)(xb + u * 186 + 2 * k2);

    float ra[6], rb[6];
    #pragma unroll
    for (int r = 0; r < 6; ++r) {
        if (r > 0) {
            // bring in conv1-out row r's two new input rows: 2r+6, 2r+7
            #pragma unroll
            for (int nn = 0; nn < 2; ++nn) {
                const int row = 2 * r + 6 + nn;
                const int slot = row & 7;
                #pragma unroll
                for (int k2 = 0; k2 < 9; ++k2)
                    *(float2*)&win[slot][2 * k2] =
                        *(const float2*)(xb + row * 186 + 2 * k2);
            }
        }
        float cl[6];
        #pragma unroll
        for (int c = 0; c < 6; ++c) {
            float acc = bv;
            #pragma unroll
            for (int u = 0; u < 8; ++u) {
                const int srow = (2 * r + u) & 7;
                #pragma unroll
                for (int v = 0; v < 8; ++v)
                    acc = fmaf(w[u * 8 + v], win[srow][2 * c + v], acc);
            }
            cl[c] = tanhf(acc);
        }
        float m01 = fmaxf(cl[0], cl[1]);
        float m23 = fmaxf(cl[2], cl[3]);
        float m45 = fmaxf(cl[4], cl[5]);
        ra[r] = fmaxf(m01, m23);
        rb[r] = fmaxf(m23, m45);
    }

    const float S = 1.57079632679489662f;
    float a0 = S * fmaxf(fmaxf(ra[0], ra[1]), fmaxf(ra[2], ra[3]));
    float a1 = S * fmaxf(fmaxf(rb[0], rb[1]), fmaxf(rb[2], rb[3]));
    float a2 = S * fmaxf(fmaxf(ra[2], ra[3]), fmaxf(ra[4], ra[5]));
    float a3 = S * fmaxf(fmaxf(rb[2], rb[3]), fmaxf(rb[4], rb[5]));

    float cs[4], sn[4];
    sincosf(0.5f * a0, &sn[0], &cs[0]);
    sincosf(0.5f * a1, &sn[1], &cs[1]);
    sincosf(0.5f * a2, &sn[2], &cs[2]);
    sincosf(0.5f * a3, &sn[3], &cs[3]);

    float c[16];
    #pragma unroll
    for (int tt = 0; tt < 16; ++tt) {
        c[tt] = ((tt & 8) ? sn[0] : cs[0]) * ((tt & 4) ? sn[1] : cs[1]) *
                ((tt & 2) ? sn[2] : cs[2]) * ((tt & 1) ? sn[3] : cs[3]);
    }

    float e0 = 0.f, e1 = 0.f, e2 = 0.f, e3 = 0.f;
    #pragma unroll
    for (int s = 0; s < 16; ++s) {
        float re = 0.f, im = 0.f;
        #pragma unroll
        for (int tt = 0; tt < 16; ++tt) {
            float2 v = V[s * 16 + tt];
            re = fmaf(v.x, c[tt], re);
            im = fmaf(v.y, c[tt], im);
        }
        float pr = re * re + im * im;
        e0 += (s & 8) ? -pr : pr;
        e1 += (s & 4) ? -pr : pr;
        e2 += (s & 2) ? -pr : pr;
        e3 += (s & 1) ? -pr : pr;
    }
    float* ob = o + b * (4 * 484) + i * 22 + j;
    ob[0]    = fmaxf(e0, 0.f);
    ob[484]  = fmaxf(e1, 0.f);
    ob[968]  = fmaxf(e2, 0.f);
    ob[1452] = fmaxf(e3, 0.f);
}

// ---------------------------------------------------------------------------
// conv2 (4->32, 4x4, s1) + relu, LDS tiled.
// ---------------------------------------------------------------------------
__global__ __launch_bounds__(640) void k_conv2t(const float* __restrict__ x,
                                                const float* __restrict__ w,
                                                const float* __restrict__ bias,
                                                float* __restrict__ y) {
    __shared__ float Xs[4 * 22 * 28];
    __shared__ float Ws[32 * 68];
    int b = blockIdx.x;
    int tid = threadIdx.x;

    const float* xb = x + b * 1936;
    for (int k = tid; k < 1936; k += 640) {
        int ic = k / 484, rem = k % 484;
        int r = rem / 22, c = rem % 22;
        Xs[ic * 616 + r * 28 + c] = xb[k];
    }
    for (int k = tid; k < 2048; k += 640) {
        Ws[(k >> 6) * 68 + (k & 63)] = w[k];
    }
    __syncthreads();

    if (tid < 608) {
        int oc = tid / 19, i = tid % 19;
        float acc[19];
        float bv = bias[oc];
        #pragma unroll
        for (int j = 0; j < 19; ++j) acc[j] = bv;
        const float* wr = &Ws[oc * 68];
        #pragma unroll
        for (int ic = 0; ic < 4; ++ic) {
            #pragma unroll
            for (int u = 0; u < 4; ++u) {
                const float* rp = &Xs[ic * 616 + (i + u) * 28];
                float xr[22];
                #pragma unroll
                for (int k = 0; k < 5; ++k)
                    *(float4*)&xr[4 * k] = *(const float4*)(rp + 4 * k);
                *(float2*)&xr[20] = *(const float2*)(rp + 20);
                float4 wv = *(const float4*)(wr + ic * 16 + u * 4);
                #pragma unroll
                for (int j = 0; j < 19; ++j) {
                    acc[j] = fmaf(wv.x, xr[j],     acc[j]);
                    acc[j] = fmaf(wv.y, xr[j + 1], acc[j]);
                    acc[j] = fmaf(wv.z, xr[j + 2], acc[j]);
                    acc[j] = fmaf(wv.w, xr[j + 3], acc[j]);
                }
            }
        }
        float* yp = y + b * 11552 + oc * 361 + i * 19;
        #pragma unroll
        for (int j = 0; j < 19; ++j) yp[j] = fmaxf(acc[j], 0.f);
    }
}

// maxpool 4x4 s1: (256,32,19,19) -> (256,32,16,16)
__global__ __launch_bounds__(256) void k_pool2(const float* __restrict__ x,
                                               float* __restrict__ y) {
    int idx = blockIdx.x * 256 + threadIdx.x;
    int j = idx % 16;
    int t = idx / 16;
    int i = t % 16;
    int c = t / 16;
    const float* xb = x + c * 361 + i * 19 + j;
    float m = -INFINITY;
    #pragma unroll
    for (int u = 0; u < 4; ++u)
        #pragma unroll
        for (int v = 0; v < 4; ++v)
            m = fmaxf(m, xb[u * 19 + v]);
    y[idx] = m;
}

// ---------------------------------------------------------------------------
// conv3 (32->64, 4x4, s1) + relu — 4 oc/thread, K-split-4, rolled k-loop.
// grid = 512, block 448 = kg(4) x ocq(16) x il(7).  (R15, unchanged)
// ---------------------------------------------------------------------------
__global__ __launch_bounds__(448) void k_conv3y(const float* __restrict__ x,
                                                const float* __restrict__ wt3,
                                                const float* __restrict__ bias,
                                                float* __restrict__ y) {
    __shared__ float Xs[32 * 200];     // 25.6 KB
    __shared__ float Rs[112 * 57];     // 25.5 KB (stride 57: conflict-free)
    int bid = blockIdx.x;
    int b = bid >> 1, h = bid & 1;
    int r0 = h * 7;
    int nr = 7 - h;
    int tid = threadIdx.x;

    const float* xb = x + b * 8192 + r0 * 16;
    #pragma unroll
    for (int it = 0; it < 3; ++it) {
        int k = it * 448 + tid;
        if (k < 1280) {
            int ic = k / 40, rem = k % 40;
            int r = rem >> 2, c4 = rem & 3;
            if (r0 + r < 16) {
                float4 v = *(const float4*)(xb + ic * 256 + r * 16 + c4 * 4);
                *(float4*)(&Xs[ic * 200 + r * 20 + c4 * 4]) = v;
            }
        }
    }
    __syncthreads();

    int kg = tid / 112;                // 0..3 -> ic group
    int t2 = tid - kg * 112;
    int ocq = t2 & 15, il = t2 >> 4;   // il 0..6
    int oc0 = ocq * 4;

    float acc[4][13];
    #pragma unroll
    for (int o = 0; o < 4; ++o)
        #pragma unroll
        for (int j = 0; j < 13; ++j) acc[o][j] = 0.f;

    const float* wb = wt3 + kg * 8192 + oc0;   // 8 ics of 1024 floats
    #pragma unroll 1
    for (int k = 0; k < 8; ++k) {
        const float* wp = wb + k * 1024;
        const float* xc = &Xs[(kg * 8 + k) * 200 + il * 20];
        #pragma unroll
        for (int u = 0; u < 4; ++u) {
            float xr[16];
            const float* rp = xc + u * 20;
            #pragma unroll
            for (int kk = 0; kk < 4; ++kk)
                *(float4*)&xr[4 * kk] = *(const float4*)(rp + 4 * kk);
            #pragma unroll
            for (int v = 0; v < 4; ++v) {
                float4 wv = *(const float4*)(wp + (u * 4 + v) * 64);
                #pragma unroll
                for (int j = 0; j < 13; ++j) {
                    acc[0][j] = fmaf(wv.x, xr[j + v], acc[0][j]);
                    acc[1][j] = fmaf(wv.y, xr[j + v], acc[1][j]);
                    acc[2][j] = fmaf(wv.z, xr[j + v], acc[2][j]);
                    acc[3][j] = fmaf(wv.w, xr[j + v], acc[3][j]);
                }
            }
        }
    }

    // 3-phase sequential reduce into kg==0
    #pragma unroll
    for (int g = 1; g < 4; ++g) {
        __syncthreads();
        if (kg == g) {
            float* rp = &Rs[t2 * 57];
            #pragma unroll
            for (int o = 0; o < 4; ++o)
                #pragma unroll
                for (int j = 0; j < 13; ++j) rp[o * 13 + j] = acc[o][j];
        }
        __syncthreads();
        if (kg == 0) {
            const float* rp = &Rs[t2 * 57];
            #pragma unroll
            for (int o = 0; o < 4; ++o)
                #pragma unroll
                for (int j = 0; j < 13; ++j)
                    acc[o][j] += rp[o * 13 + j];
        }
    }

    if (kg == 0 && il < nr) {
        float* yp = y + b * 10816 + oc0 * 169 + (r0 + il) * 13;
        #pragma unroll
        for (int o = 0; o < 4; ++o) {
            float bv = bias[oc0 + o];
            #pragma unroll
            for (int j = 0; j < 13; ++j)
                yp[o * 169 + j] = fmaxf(acc[o][j] + bv, 0.f);
        }
    }
}

// ---------------------------------------------------------------------------
// conv4 (64->128, 4x4, s2) partials — 4 oc/thread, K-split-4, rolled k-loop,
// pool3 fused into staging.  grid = 512, block 640 = kg(4) x ocq(32) x i(5).
// ---------------------------------------------------------------------------
__global__ __launch_bounds__(640) void k_conv4y(const float* __restrict__ x3,
                                                const float* __restrict__ wt4,
                                                float* __restrict__ part) {
    __shared__ float Xs[32 * 144];     // 18.4 KB
    __shared__ float Rs[160 * 21];     // 13.4 KB
    int bid = blockIdx.x;
    int b = bid >> 1, kq = bid & 1;
    int tid = threadIdx.x;

    // stage 32 channels of pooled (12x12) from conv3 output (13x13)
    const float* gb = x3 + b * 10816 + kq * 32 * 169;
    for (int k = tid; k < 4608; k += 640) {
        int ic = k / 144, rc = k % 144;
        int r = rc / 12, c = rc % 12;
        const float* g = gb + ic * 169 + r * 13 + c;
        Xs[k] = fmaxf(fmaxf(g[0], g[1]), fmaxf(g[13], g[14]));
    }
    __syncthreads();

    int kg = tid / 160;                // 0..3
    int t2 = tid - kg * 160;
    int ocq = t2 & 31, i = t2 >> 5;    // i 0..4
    int oc0 = ocq * 4;

    float acc[4][5];
    #pragma unroll
    for (int o = 0; o < 4; ++o)
        #pragma unroll
        for (int j = 0; j < 5; ++j) acc[o][j] = 0.f;

    const float* wb = wt4 + (kq * 32 + kg * 8) * 2048 + oc0;
    #pragma unroll 1
    for (int k = 0; k < 8; ++k) {
        const float* wp = wb + k * 2048;
        const float* xc = &Xs[(kg * 8 + k) * 144];
        #pragma unroll
        for (int u = 0; u < 4; ++u) {
            const float* rp = xc + (2 * i + u) * 12;
            float xr[12];
            #pragma unroll
            for (int kk = 0; kk < 3; ++kk)
                *(float4*)&xr[4 * kk] = *(const float4*)(rp + 4 * kk);
            #pragma unroll
            for (int v = 0; v < 4; ++v) {
                float4 wv = *(const float4*)(wp + (u * 4 + v) * 128);
                #pragma unroll
                for (int j = 0; j < 5; ++j) {
                    float xv = xr[2 * j + v];
                    acc[0][j] = fmaf(wv.x, xv, acc[0][j]);
                    acc[1][j] = fmaf(wv.y, xv, acc[1][j]);
                    acc[2][j] = fmaf(wv.z, xv, acc[2][j]);
                    acc[3][j] = fmaf(wv.w, xv, acc[3][j]);
                }
            }
        }
    }

    #pragma unroll
    for (int g = 1; g < 4; ++g) {
        __syncthreads();
        if (kg == g) {
            float* rp = &Rs[t2 * 21];
            #pragma unroll
            for (int o = 0; o < 4; ++o)
                #pragma unroll
                for (int j = 0; j < 5; ++j) rp[o * 5 + j] = acc[o][j];
        }
        __syncthreads();
        if (kg == 0) {
            const float* rp = &Rs[t2 * 21];
            #pragma unroll
            for (int o = 0; o < 4; ++o)
                #pragma unroll
                for (int j = 0; j < 5; ++j) acc[o][j] += rp[o * 5 + j];
        }
    }

    if (kg == 0) {
        float* pp = part + kq * 819200 + b * 3200 + oc0 * 25 + i * 5;
        #pragma unroll
        for (int o = 0; o < 4; ++o)
            #pragma unroll
            for (int j = 0; j < 5; ++j) pp[o * 25 + j] = acc[o][j];
    }
}

// ---------------------------------------------------------------------------
// fc1 fused with c4red: x[img][k] = relu(part0[k] + part1[k] + b4[k/25]).
// (256,3200) @ (128,3200)^T + relu.
// ---------------------------------------------------------------------------
__global__ __launch_bounds__(256) void k_fc1f(const float* __restrict__ part,
                                              const float* __restrict__ w,
                                              const float* __restrict__ b4,
                                              const float* __restrict__ bias,
                                              float* __restrict__ y) {
    __shared__ float Ls[4][32][65];
    int bid = blockIdx.x;
    int ig = bid >> 2, ocg = bid & 3;
    int imgB = ig * 4, ocB = ocg * 32;
    int tid = threadIdx.x, lane = tid & 63, wv = tid >> 6;
    int ocW = ocB + wv * 8;

    float acc[8][4];
    #pragma unroll
    for (int o = 0; o < 8; ++o)
        #pragma unroll
        for (int m = 0; m < 4; ++m) acc[o][m] = 0.f;

    for (int it = 0; it < 25; ++it) {
        int k = it * 128 + lane * 2;
        float ba = b4[k / 25];
        float bb = b4[(k + 1) / 25];
        float2 xv[4];
        #pragma unroll
        for (int m = 0; m < 4; ++m) {
            int base = (imgB + m) * 3200 + k;
            float2 p0 = *(const float2*)&part[base];
            float2 p1 = *(const float2*)&part[base + 819200];
            xv[m].x = fmaxf(p0.x + p1.x + ba, 0.f);
            xv[m].y = fmaxf(p0.y + p1.y + bb, 0.f);
        }
        #pragma unroll
        for (int o = 0; o < 8; ++o) {
            float2 wvv = *(const float2*)&w[(ocW + o) * 3200 + k];
            #pragma unroll
            for (int m = 0; m < 4; ++m) {
                acc[o][m] = fmaf(wvv.x, xv[m].x, acc[o][m]);
                acc[o][m] = fmaf(wvv.y, xv[m].y, acc[o][m]);
            }
        }
    }
    #pragma unroll
    for (int o = 0; o < 8; ++o)
        #pragma unroll
        for (int m = 0; m < 4; ++m)
            Ls[wv][o * 4 + m][lane] = acc[o][m];
    __syncthreads();

    if (tid < 128) {
        int w2 = tid >> 5, r = tid & 31;
        const float* p = Ls[w2][r];
        float s = 0.f;
        #pragma unroll
        for (int c = 0; c < 64; ++c) s += p[c];
        int o = r >> 2, m = r & 3;
        int oc = ocB + w2 * 8 + o;
        y[(imgB + m) * 128 + oc] = fmaxf(s + bias[oc], 0.f);
    }
}

// ---------------------------------------------------------------------------
// fused fc2+relu, fc3+relu, fc4+log_softmax.
// ---------------------------------------------------------------------------
__global__ __launch_bounds__(64) void k_fc_tail(const float* __restrict__ x,
                                                const float* __restrict__ w2,
                                                const float* __restrict__ b2,
                                                const float* __restrict__ w3,
                                                const float* __restrict__ b3,
                                                const float* __restrict__ w4,
                                                const float* __restrict__ b4,
                                                float* __restrict__ out) {
    __shared__ float xs[128], h2[64], h3[16];
    int img = blockIdx.x;
    int lane = threadIdx.x;

    *(float2*)&xs[lane * 2] = *(const float2*)&x[img * 128 + lane * 2];
    __syncthreads();

    float a = b2[lane];
    const float4* wp = (const float4*)&w2[lane * 128];
    const float4* xp = (const float4*)xs;
    #pragma unroll
    for (int k = 0; k < 32; ++k) {
        float4 wv = wp[k], xv = xp[k];
        a = fmaf(wv.x, xv.x, a);
        a = fmaf(wv.y, xv.y, a);
        a = fmaf(wv.z, xv.z, a);
        a = fmaf(wv.w, xv.w, a);
    }
    h2[lane] = fmaxf(a, 0.f);
    __syncthreads();

    if (lane < 16) {
        float a3 = b3[lane];
        const float4* w3p = (const float4*)&w3[lane * 64];
        const float4* h2p = (const float4*)h2;
        #pragma unroll
        for (int k = 0; k < 16; ++k) {
            float4 wv = w3p[k], xv = h2p[k];
            a3 = fmaf(wv.x, xv.x, a3);
            a3 = fmaf(wv.y, xv.y, a3);
            a3 = fmaf(wv.z, xv.z, a3);
            a3 = fmaf(wv.w, xv.w, a3);
        }
        h3[lane] = fmaxf(a3, 0.f);
    }
    __syncthreads();

    if (lane == 0) {
        float z0 = b4[0], z1 = b4[1];
        #pragma unroll
        for (int k = 0; k < 16; ++k) {
            z0 = fmaf(w4[k],      h3[k], z0);
            z1 = fmaf(w4[16 + k], h3[k], z1);
        }
        float m = fmaxf(z0, z1);
        float lse = m + logf(expf(z0 - m) + expf(z1 - m));
        out[img * 2 + 0] = z0 - lse;
        out[img * 2 + 1] = z1 - lse;
    }
}

// ---------------------------------------------------------------------------
extern "C" void kernel_launch(void* const* d_in, const int* in_sizes, int n_in,
                              void* d_out, int out_size, void* d_ws, size_t ws_size,
                              hipStream_t stream) {
    const float* x       = (const float*)d_in[0];
    const float* conv1_w = (const float*)d_in[1];
    const float* conv1_b = (const float*)d_in[2];
    const float* q_w     = (const float*)d_in[3];
    const float* conv2_w = (const float*)d_in[4];
    const float* conv2_b = (const float*)d_in[5];
    const float* conv3_w = (const float*)d_in[6];
    const float* conv3_b = (const float*)d_in[7];
    const float* conv4_w = (const float*)d_in[8];
    const float* conv4_b = (const float*)d_in[9];
    const float* fc1_w   = (const float*)d_in[10];
    const float* fc1_b   = (const float*)d_in[11];
    const float* fc2_w   = (const float*)d_in[12];
    const float* fc2_b   = (const float*)d_in[13];
    const float* fc3_w   = (const float*)d_in[14];
    const float* fc3_b   = (const float*)d_in[15];
    const float* fc4_w   = (const float*)d_in[16];
    const float* fc4_b   = (const float*)d_in[17];
    float* out = (float*)d_out;

    char* ws = (char*)d_ws;
    float2* V  = (float2*)ws;                          // 2 KB
    float* A   = (float*)(ws + 4096);                  // 12 MB region
    float* B   = (float*)(ws + 12587008);              // 8.5 MB region
    float* WT3 = (float*)(ws + 21499904);              // 128 KB
    float* WT4 = (float*)(ws + 21639168);              // 512 KB

    k_build_V<<<1, 256, 0, stream>>>(q_w, V);
    k_wtrans<<<640, 256, 0, stream>>>(conv3_w, conv4_w, WT3, WT4);
    k_cq<<<484, 256, 0, stream>>>(x, conv1_w, conv1_b, V, B);
    k_conv2t<<<256, 640, 0, stream>>>(B, conv2_w, conv2_b, A);
    k_pool2<<<8192, 256, 0, stream>>>(A, B);
    k_conv3y<<<512, 448, 0, stream>>>(B, WT3, conv3_b, A);
    k_conv4y<<<512, 640, 0, stream>>>(A, WT4, B);
    k_fc1f<<<256, 256, 0, stream>>>(B, fc1_w, conv4_b, fc1_b, A);
    k_fc_tail<<<256, 64, 0, stream>>>(A, fc2_w, fc2_b, fc3_w, fc3_b,
                                      fc4_w, fc4_b, out);
}

// Round 21
// 151.623 us; speedup vs baseline: 1.0850x; 1.0509x over previous
//
#include <hip/hip_runtime.h>
#include <hip/hip_bf16.h>
#include <math.h>

// ---------------------------------------------------------------------------
// Hybrid_QuanvModel — round 21: R20's conv2+pool2 fusion with FIXED buffer
// routing (A/B ping-pong respects region sizes; R20 overflowed B with
// conv3's 10.6 MB output).  8 launches.
// ---------------------------------------------------------------------------

__device__ __forceinline__ float2 cmul(float2 a, float2 b) {
    return make_float2(a.x * b.x - a.y * b.y, a.x * b.y + a.y * b.x);
}
__device__ __forceinline__ float2 cfma(float2 a, float2 b, float2 acc) {
    acc.x += a.x * b.x - a.y * b.y;
    acc.y += a.x * b.y + a.y * b.x;
    return acc;
}

// ---------------------------------------------------------------------------
// Build V[s][t] = U3[s][t] * (-i)^popcount(t)   (16x16 complex)
// ---------------------------------------------------------------------------
__global__ __launch_bounds__(256) void k_build_V(const float* __restrict__ qw,
                                                 float2* __restrict__ Vout) {
    __shared__ float2 rot[3][4][2][2];
    __shared__ float2 L[16][16];
    __shared__ float2 U[16][16];
    __shared__ float2 T[16][16];

    int tid = threadIdx.x;
    if (tid < 12) {
        int l = tid >> 2, q = tid & 3;
        float phi = qw[(l * 4 + q) * 3 + 0];
        float th  = qw[(l * 4 + q) * 3 + 1];
        float om  = qw[(l * 4 + q) * 3 + 2];
        float c, s;
        sincosf(0.5f * th, &s, &c);
        float sa, ca, sb, cb;
        sincosf(0.5f * (phi + om), &sa, &ca);
        sincosf(0.5f * (phi - om), &sb, &cb);
        rot[l][q][0][0] = make_float2( ca * c, -sa * c);
        rot[l][q][0][1] = make_float2(-cb * s, -sb * s);
        rot[l][q][1][0] = make_float2( cb * s, -sb * s);
        rot[l][q][1][1] = make_float2( ca * c,  sa * c);
    }
    int s = tid >> 4, t = tid & 15;
    U[s][t] = make_float2((s == t) ? 1.f : 0.f, 0.f);
    __syncthreads();

    for (int l = 0; l < 3; ++l) {
        int r = l + 1;
        int ss = s;
        for (int i = 3; i >= 0; --i) {
            int c_ = i, t_ = (i + r) & 3;
            if ((ss >> (3 - c_)) & 1) ss ^= 1 << (3 - t_);
        }
        float2 v = make_float2(1.f, 0.f);
        #pragma unroll
        for (int q = 0; q < 4; ++q) {
            int bs = (ss >> (3 - q)) & 1;
            int bt = (t  >> (3 - q)) & 1;
            v = cmul(v, rot[l][q][bs][bt]);
        }
        L[s][t] = v;
        __syncthreads();
        float2 acc = make_float2(0.f, 0.f);
        #pragma unroll
        for (int k = 0; k < 16; ++k) acc = cfma(L[s][k], U[k][t], acc);
        T[s][t] = acc;
        __syncthreads();
        U[s][t] = T[s][t];
        __syncthreads();
    }
    float2 acc = make_float2(0.f, 0.f);
    #pragma unroll
    for (int k = 0; k < 16; ++k) acc = cfma(U[s][k], U[k][t], acc);
    T[s][t] = acc;
    __syncthreads();
    acc = make_float2(0.f, 0.f);
    #pragma unroll
    for (int k = 0; k < 16; ++k) acc = cfma(T[s][k], U[k][t], acc);
    int pc = __popc(t) & 3;
    float2 v;
    if      (pc == 0) v = acc;
    else if (pc == 1) v = make_float2( acc.y, -acc.x);
    else if (pc == 2) v = make_float2(-acc.x, -acc.y);
    else              v = make_float2(-acc.y,  acc.x);
    Vout[s * 16 + t] = v;
}

// ---------------------------------------------------------------------------
// weight transpose: w3 (64,32,4,4) -> wt3[ic][tap][oc] (32,16,64)
//                   w4 (128,64,4,4) -> wt4[ic][tap][oc] (64,16,128)
// ---------------------------------------------------------------------------
__global__ __launch_bounds__(256) void k_wtrans(const float* __restrict__ w3,
                                                const float* __restrict__ w4,
                                                float* __restrict__ wt3,
                                                float* __restrict__ wt4) {
    int idx = blockIdx.x * 256 + threadIdx.x;
    if (idx < 32768) {
        int oc = idx & 63, tap = (idx >> 6) & 15, ic = idx >> 10;
        wt3[idx] = w3[oc * 512 + ic * 16 + tap];
    } else {
        int o = idx - 32768;
        int oc = o & 127, tap = (o >> 7) & 15, ic = o >> 11;
        wt4[o] = w4[oc * 1024 + ic * 16 + tap];
    }
}

// ---------------------------------------------------------------------------
// fused conv1(8x8,s2)+tanh + maxpool(4,2)*pi/2 + quanv + relu:
// x:(256,186,186) -> o:(256,4,22,22).
// ---------------------------------------------------------------------------
__global__ __launch_bounds__(256) void k_cq(const float* __restrict__ x,
                                            const float* __restrict__ w,
                                            const float* __restrict__ bias,
                                            const float2* __restrict__ Vg,
                                            float* __restrict__ o) {
    __shared__ float2 V[256];
    V[threadIdx.x] = Vg[threadIdx.x];
    __syncthreads();

    int idx = blockIdx.x * 256 + threadIdx.x;      // 484*256 = 256*22*22
    int j = idx % 22;
    int t = idx / 22;
    int i = t % 22;
    int b = t / 22;

    const float* xb = x + b * 34596 + (8 * i) * 186 + 8 * j;
    float bv = bias[0];

    float win[8][18];
    #pragma unroll
    for (int u = 0; u < 8; ++u)
        #pragma unroll
        for (int k2 = 0; k2 < 9; ++k2)
            *(float2*)&win[u][2 * k2] = *(const float2*)(xb + u * 186 + 2 * k2);

    float ra[6], rb[6];
    #pragma unroll
    for (int r = 0; r < 6; ++r) {
        if (r > 0) {
            #pragma unroll
            for (int nn = 0; nn < 2; ++nn) {
                const int row = 2 * r + 6 + nn;
                const int slot = row & 7;
                #pragma unroll
                for (int k2 = 0; k2 < 9; ++k2)
                    *(float2*)&win[slot][2 * k2] =
                        *(const float2*)(xb + row * 186 + 2 * k2);
            }
        }
        float cl[6];
        #pragma unroll
        for (int c = 0; c < 6; ++c) {
            float acc = bv;
            #pragma unroll
            for (int u = 0; u < 8; ++u) {
                const int srow = (2 * r + u) & 7;
                #pragma unroll
                for (int v = 0; v < 8; ++v)
                    acc = fmaf(w[u * 8 + v], win[srow][2 * c + v], acc);
            }
            cl[c] = tanhf(acc);
        }
        float m01 = fmaxf(cl[0], cl[1]);
        float m23 = fmaxf(cl[2], cl[3]);
        float m45 = fmaxf(cl[4], cl[5]);
        ra[r] = fmaxf(m01, m23);
        rb[r] = fmaxf(m23, m45);
    }

    const float S = 1.57079632679489662f;
    float a0 = S * fmaxf(fmaxf(ra[0], ra[1]), fmaxf(ra[2], ra[3]));
    float a1 = S * fmaxf(fmaxf(rb[0], rb[1]), fmaxf(rb[2], rb[3]));
    float a2 = S * fmaxf(fmaxf(ra[2], ra[3]), fmaxf(ra[4], ra[5]));
    float a3 = S * fmaxf(fmaxf(rb[2], rb[3]), fmaxf(rb[4], rb[5]));

    float cs[4], sn[4];
    sincosf(0.5f * a0, &sn[0], &cs[0]);
    sincosf(0.5f * a1, &sn[1], &cs[1]);
    sincosf(0.5f * a2, &sn[2], &cs[2]);
    sincosf(0.5f * a3, &sn[3], &cs[3]);

    float c[16];
    #pragma unroll
    for (int tt = 0; tt < 16; ++tt) {
        c[tt] = ((tt & 8) ? sn[0] : cs[0]) * ((tt & 4) ? sn[1] : cs[1]) *
                ((tt & 2) ? sn[2] : cs[2]) * ((tt & 1) ? sn[3] : cs[3]);
    }

    float e0 = 0.f, e1 = 0.f, e2 = 0.f, e3 = 0.f;
    #pragma unroll
    for (int s = 0; s < 16; ++s) {
        float re = 0.f, im = 0.f;
        #pragma unroll
        for (int tt = 0; tt < 16; ++tt) {
            float2 v = V[s * 16 + tt];
            re = fmaf(v.x, c[tt], re);
            im = fmaf(v.y, c[tt], im);
        }
        float pr = re * re + im * im;
        e0 += (s & 8) ? -pr : pr;
        e1 += (s & 4) ? -pr : pr;
        e2 += (s & 2) ? -pr : pr;
        e3 += (s & 1) ? -pr : pr;
    }
    float* ob = o + b * (4 * 484) + i * 22 + j;
    ob[0]    = fmaxf(e0, 0.f);
    ob[484]  = fmaxf(e1, 0.f);
    ob[968]  = fmaxf(e2, 0.f);
    ob[1452] = fmaxf(e3, 0.f);
}

// ---------------------------------------------------------------------------
// conv2 (4->32, 4x4, s1) + relu + maxpool(4,1) fused:
// (256,4,22,22) -> (256,32,16,16).  One img/block, block 640.
// ---------------------------------------------------------------------------
__global__ __launch_bounds__(640) void k_conv2p(const float* __restrict__ x,
                                                const float* __restrict__ w,
                                                const float* __restrict__ bias,
                                                float* __restrict__ y) {
    __shared__ float Xs[4 * 22 * 28];    // 9.9 KB
    __shared__ float Ws[32 * 68];        // 8.7 KB
    __shared__ float Ps[32 * 323];       // 41.3 KB: [oc][i*17 + j]
    int b = blockIdx.x;
    int tid = threadIdx.x;

    const float* xb = x + b * 1936;
    for (int k = tid; k < 1936; k += 640) {
        int ic = k / 484, rem = k % 484;
        int r = rem / 22, c = rem % 22;
        Xs[ic * 616 + r * 28 + c] = xb[k];
    }
    for (int k = tid; k < 2048; k += 640) {
        Ws[(k >> 6) * 68 + (k & 63)] = w[k];
    }
    __syncthreads();

    if (tid < 608) {
        int oc = tid / 19, i = tid % 19;
        float acc[19];
        float bv = bias[oc];
        #pragma unroll
        for (int j = 0; j < 19; ++j) acc[j] = bv;
        const float* wr = &Ws[oc * 68];
        #pragma unroll
        for (int ic = 0; ic < 4; ++ic) {
            #pragma unroll
            for (int u = 0; u < 4; ++u) {
                const float* rp = &Xs[ic * 616 + (i + u) * 28];
                float xr[22];
                #pragma unroll
                for (int k = 0; k < 5; ++k)
                    *(float4*)&xr[4 * k] = *(const float4*)(rp + 4 * k);
                *(float2*)&xr[20] = *(const float2*)(rp + 20);
                float4 wv = *(const float4*)(wr + ic * 16 + u * 4);
                #pragma unroll
                for (int j = 0; j < 19; ++j) {
                    acc[j] = fmaf(wv.x, xr[j],     acc[j]);
                    acc[j] = fmaf(wv.y, xr[j + 1], acc[j]);
                    acc[j] = fmaf(wv.z, xr[j + 2], acc[j]);
                    acc[j] = fmaf(wv.w, xr[j + 3], acc[j]);
                }
            }
        }
        // relu + horizontal 4-max
        float rr[19];
        #pragma unroll
        for (int j = 0; j < 19; ++j) rr[j] = fmaxf(acc[j], 0.f);
        float* pp = &Ps[oc * 323 + i * 17];
        #pragma unroll
        for (int j = 0; j < 16; ++j)
            pp[j] = fmaxf(fmaxf(rr[j], rr[j + 1]), fmaxf(rr[j + 2], rr[j + 3]));
    }
    __syncthreads();

    if (tid < 512) {
        int oc = tid >> 4, pi = tid & 15;
        const float* p0 = &Ps[oc * 323 + pi * 17];
        float* yp = y + b * 8192 + oc * 256 + pi * 16;
        #pragma unroll
        for (int pj = 0; pj < 16; ++pj) {
            float m = fmaxf(fmaxf(p0[pj], p0[17 + pj]),
                            fmaxf(p0[34 + pj], p0[51 + pj]));
            yp[pj] = m;
        }
    }
}

// ---------------------------------------------------------------------------
// conv3 (32->64, 4x4, s1) + relu — 4 oc/thread, K-split-4, rolled k-loop.
// grid = 512, block 448 = kg(4) x ocq(16) x il(7).
// ---------------------------------------------------------------------------
__global__ __launch_bounds__(448) void k_conv3y(const float* __restrict__ x,
                                                const float* __restrict__ wt3,
                                                const float* __restrict__ bias,
                                                float* __restrict__ y) {
    __shared__ float Xs[32 * 200];     // 25.6 KB
    __shared__ float Rs[112 * 57];     // 25.5 KB (stride 57: conflict-free)
    int bid = blockIdx.x;
    int b = bid >> 1, h = bid & 1;
    int r0 = h * 7;
    int nr = 7 - h;
    int tid = threadIdx.x;

    const float* xb = x + b * 8192 + r0 * 16;
    #pragma unroll
    for (int it = 0; it < 3; ++it) {
        int k = it * 448 + tid;
        if (k < 1280) {
            int ic = k / 40, rem = k % 40;
            int r = rem >> 2, c4 = rem & 3;
            if (r0 + r < 16) {
                float4 v = *(const float4*)(xb + ic * 256 + r * 16 + c4 * 4);
                *(float4*)(&Xs[ic * 200 + r * 20 + c4 * 4]) = v;
            }
        }
    }
    __syncthreads();

    int kg = tid / 112;                // 0..3 -> ic group
    int t2 = tid - kg * 112;
    int ocq = t2 & 15, il = t2 >> 4;   // il 0..6
    int oc0 = ocq * 4;

    float acc[4][13];
    #pragma unroll
    for (int o = 0; o < 4; ++o)
        #pragma unroll
        for (int j = 0; j < 13; ++j) acc[o][j] = 0.f;

    const float* wb = wt3 + kg * 8192 + oc0;   // 8 ics of 1024 floats
    #pragma unroll 1
    for (int k = 0; k < 8; ++k) {
        const float* wp = wb + k * 1024;
        const float* xc = &Xs[(kg * 8 + k) * 200 + il * 20];
        #pragma unroll
        for (int u = 0; u < 4; ++u) {
            float xr[16];
            const float* rp = xc + u * 20;
            #pragma unroll
            for (int kk = 0; kk < 4; ++kk)
                *(float4*)&xr[4 * kk] = *(const float4*)(rp + 4 * kk);
            #pragma unroll
            for (int v = 0; v < 4; ++v) {
                float4 wv = *(const float4*)(wp + (u * 4 + v) * 64);
                #pragma unroll
                for (int j = 0; j < 13; ++j) {
                    acc[0][j] = fmaf(wv.x, xr[j + v], acc[0][j]);
                    acc[1][j] = fmaf(wv.y, xr[j + v], acc[1][j]);
                    acc[2][j] = fmaf(wv.z, xr[j + v], acc[2][j]);
                    acc[3][j] = fmaf(wv.w, xr[j + v], acc[3][j]);
                }
            }
        }
    }

    // 3-phase sequential reduce into kg==0
    #pragma unroll
    for (int g = 1; g < 4; ++g) {
        __syncthreads();
        if (kg == g) {
            float* rp = &Rs[t2 * 57];
            #pragma unroll
            for (int o = 0; o < 4; ++o)
                #pragma unroll
                for (int j = 0; j < 13; ++j) rp[o * 13 + j] = acc[o][j];
        }
        __syncthreads();
        if (kg == 0) {
            const float* rp = &Rs[t2 * 57];
            #pragma unroll
            for (int o = 0; o < 4; ++o)
                #pragma unroll
                for (int j = 0; j < 13; ++j)
                    acc[o][j] += rp[o * 13 + j];
        }
    }

    if (kg == 0 && il < nr) {
        float* yp = y + b * 10816 + oc0 * 169 + (r0 + il) * 13;
        #pragma unroll
        for (int o = 0; o < 4; ++o) {
            float bv = bias[oc0 + o];
            #pragma unroll
            for (int j = 0; j < 13; ++j)
                yp[o * 169 + j] = fmaxf(acc[o][j] + bv, 0.f);
        }
    }
}

// ---------------------------------------------------------------------------
// conv4 (64->128, 4x4, s2) partials — 4 oc/thread, K-split-4, rolled k-loop,
// pool3 fused into staging.  grid = 512, block 640 = kg(4) x ocq(32) x i(5).
// ---------------------------------------------------------------------------
__global__ __launch_bounds__(640) void k_conv4y(const float* __restrict__ x3,
                                                const float* __restrict__ wt4,
                                                float* __restrict__ part) {
    __shared__ float Xs[32 * 144];     // 18.4 KB
    __shared__ float Rs[160 * 21];     // 13.4 KB
    int bid = blockIdx.x;
    int b = bid >> 1, kq = bid & 1;
    int tid = threadIdx.x;

    // stage 32 channels of pooled (12x12) from conv3 output (13x13)
    const float* gb = x3 + b * 10816 + kq * 32 * 169;
    for (int k = tid; k < 4608; k += 640) {
        int ic = k / 144, rc = k % 144;
        int r = rc / 12, c = rc % 12;
        const float* g = gb + ic * 169 + r * 13 + c;
        Xs[k] = fmaxf(fmaxf(g[0], g[1]), fmaxf(g[13], g[14]));
    }
    __syncthreads();

    int kg = tid / 160;                // 0..3
    int t2 = tid - kg * 160;
    int ocq = t2 & 31, i = t2 >> 5;    // i 0..4
    int oc0 = ocq * 4;

    float acc[4][5];
    #pragma unroll
    for (int o = 0; o < 4; ++o)
        #pragma unroll
        for (int j = 0; j < 5; ++j) acc[o][j] = 0.f;

    const float* wb = wt4 + (kq * 32 + kg * 8) * 2048 + oc0;
    #pragma unroll 1
    for (int k = 0; k < 8; ++k) {
        const float* wp = wb + k * 2048;
        const float* xc = &Xs[(kg * 8 + k) * 144];
        #pragma unroll
        for (int u = 0; u < 4; ++u) {
            const float* rp = xc + (2 * i + u) * 12;
            float xr[12];
            #pragma unroll
            for (int kk = 0; kk < 3; ++kk)
                *(float4*)&xr[4 * kk] = *(const float4*)(rp + 4 * kk);
            #pragma unroll
            for (int v = 0; v < 4; ++v) {
                float4 wv = *(const float4*)(wp + (u * 4 + v) * 128);
                #pragma unroll
                for (int j = 0; j < 5; ++j) {
                    float xv = xr[2 * j + v];
                    acc[0][j] = fmaf(wv.x, xv, acc[0][j]);
                    acc[1][j] = fmaf(wv.y, xv, acc[1][j]);
                    acc[2][j] = fmaf(wv.z, xv, acc[2][j]);
                    acc[3][j] = fmaf(wv.w, xv, acc[3][j]);
                }
            }
        }
    }

    #pragma unroll
    for (int g = 1; g < 4; ++g) {
        __syncthreads();
        if (kg == g) {
            float* rp = &Rs[t2 * 21];
            #pragma unroll
            for (int o = 0; o < 4; ++o)
                #pragma unroll
                for (int j = 0; j < 5; ++j) rp[o * 5 + j] = acc[o][j];
        }
        __syncthreads();
        if (kg == 0) {
            const float* rp = &Rs[t2 * 21];
            #pragma unroll
            for (int o = 0; o < 4; ++o)
                #pragma unroll
                for (int j = 0; j < 5; ++j) acc[o][j] += rp[o * 5 + j];
        }
    }

    if (kg == 0) {
        float* pp = part + kq * 819200 + b * 3200 + oc0 * 25 + i * 5;
        #pragma unroll
        for (int o = 0; o < 4; ++o)
            #pragma unroll
            for (int j = 0; j < 5; ++j) pp[o * 25 + j] = acc[o][j];
    }
}

// ---------------------------------------------------------------------------
// fc1 fused with c4red: x[img][k] = relu(part0[k] + part1[k] + b4[k/25]).
// ---------------------------------------------------------------------------
__global__ __launch_bounds__(256) void k_fc1f(const float* __restrict__ part,
                                              const float* __restrict__ w,
                                              const float* __restrict__ b4,
                                              const float* __restrict__ bias,
                                              float* __restrict__ y) {
    __shared__ float Ls[4][32][65];
    int bid = blockIdx.x;
    int ig = bid >> 2, ocg = bid & 3;
    int imgB = ig * 4, ocB = ocg * 32;
    int tid = threadIdx.x, lane = tid & 63, wv = tid >> 6;
    int ocW = ocB + wv * 8;

    float acc[8][4];
    #pragma unroll
    for (int o = 0; o < 8; ++o)
        #pragma unroll
        for (int m = 0; m < 4; ++m) acc[o][m] = 0.f;

    for (int it = 0; it < 25; ++it) {
        int k = it * 128 + lane * 2;
        float ba = b4[k / 25];
        float bb = b4[(k + 1) / 25];
        float2 xv[4];
        #pragma unroll
        for (int m = 0; m < 4; ++m) {
            int base = (imgB + m) * 3200 + k;
            float2 p0 = *(const float2*)&part[base];
            float2 p1 = *(const float2*)&part[base + 819200];
            xv[m].x = fmaxf(p0.x + p1.x + ba, 0.f);
            xv[m].y = fmaxf(p0.y + p1.y + bb, 0.f);
        }
        #pragma unroll
        for (int o = 0; o < 8; ++o) {
            float2 wvv = *(const float2*)&w[(ocW + o) * 3200 + k];
            #pragma unroll
            for (int m = 0; m < 4; ++m) {
                acc[o][m] = fmaf(wvv.x, xv[m].x, acc[o][m]);
                acc[o][m] = fmaf(wvv.y, xv[m].y, acc[o][m]);
            }
        }
    }
    #pragma unroll
    for (int o = 0; o < 8; ++o)
        #pragma unroll
        for (int m = 0; m < 4; ++m)
            Ls[wv][o * 4 + m][lane] = acc[o][m];
    __syncthreads();

    if (tid < 128) {
        int w2 = tid >> 5, r = tid & 31;
        const float* p = Ls[w2][r];
        float s = 0.f;
        #pragma unroll
        for (int c = 0; c < 64; ++c) s += p[c];
        int o = r >> 2, m = r & 3;
        int oc = ocB + w2 * 8 + o;
        y[(imgB + m) * 128 + oc] = fmaxf(s + bias[oc], 0.f);
    }
}

// ---------------------------------------------------------------------------
// fused fc2+relu, fc3+relu, fc4+log_softmax.
// ---------------------------------------------------------------------------
__global__ __launch_bounds__(64) void k_fc_tail(const float* __restrict__ x,
                                                const float* __restrict__ w2,
                                                const float* __restrict__ b2,
                                                const float* __restrict__ w3,
                                                const float* __restrict__ b3,
                                                const float* __restrict__ w4,
                                                const float* __restrict__ b4,
                                                float* __restrict__ out) {
    __shared__ float xs[128], h2[64], h3[16];
    int img = blockIdx.x;
    int lane = threadIdx.x;

    *(float2*)&xs[lane * 2] = *(const float2*)&x[img * 128 + lane * 2];
    __syncthreads();

    float a = b2[lane];
    const float4* wp = (const float4*)&w2[lane * 128];
    const float4* xp = (const float4*)xs;
    #pragma unroll
    for (int k = 0; k < 32; ++k) {
        float4 wv = wp[k], xv = xp[k];
        a = fmaf(wv.x, xv.x, a);
        a = fmaf(wv.y, xv.y, a);
        a = fmaf(wv.z, xv.z, a);
        a = fmaf(wv.w, xv.w, a);
    }
    h2[lane] = fmaxf(a, 0.f);
    __syncthreads();

    if (lane < 16) {
        float a3 = b3[lane];
        const float4* w3p = (const float4*)&w3[lane * 64];
        const float4* h2p = (const float4*)h2;
        #pragma unroll
        for (int k = 0; k < 16; ++k) {
            float4 wv = w3p[k], xv = h2p[k];
            a3 = fmaf(wv.x, xv.x, a3);
            a3 = fmaf(wv.y, xv.y, a3);
            a3 = fmaf(wv.z, xv.z, a3);
            a3 = fmaf(wv.w, xv.w, a3);
        }
        h3[lane] = fmaxf(a3, 0.f);
    }
    __syncthreads();

    if (lane == 0) {
        float z0 = b4[0], z1 = b4[1];
        #pragma unroll
        for (int k = 0; k < 16; ++k) {
            z0 = fmaf(w4[k],      h3[k], z0);
            z1 = fmaf(w4[16 + k], h3[k], z1);
        }
        float m = fmaxf(z0, z1);
        float lse = m + logf(expf(z0 - m) + expf(z1 - m));
        out[img * 2 + 0] = z0 - lse;
        out[img * 2 + 1] = z1 - lse;
    }
}

// ---------------------------------------------------------------------------
extern "C" void kernel_launch(void* const* d_in, const int* in_sizes, int n_in,
                              void* d_out, int out_size, void* d_ws, size_t ws_size,
                              hipStream_t stream) {
    const float* x       = (const float*)d_in[0];
    const float* conv1_w = (const float*)d_in[1];
    const float* conv1_b = (const float*)d_in[2];
    const float* q_w     = (const float*)d_in[3];
    const float* conv2_w = (const float*)d_in[4];
    const float* conv2_b = (const float*)d_in[5];
    const float* conv3_w = (const float*)d_in[6];
    const float* conv3_b = (const float*)d_in[7];
    const float* conv4_w = (const float*)d_in[8];
    const float* conv4_b = (const float*)d_in[9];
    const float* fc1_w   = (const float*)d_in[10];
    const float* fc1_b   = (const float*)d_in[11];
    const float* fc2_w   = (const float*)d_in[12];
    const float* fc2_b   = (const float*)d_in[13];
    const float* fc3_w   = (const float*)d_in[14];
    const float* fc3_b   = (const float*)d_in[15];
    const float* fc4_w   = (const float*)d_in[16];
    const float* fc4_b   = (const float*)d_in[17];
    float* out = (float*)d_out;

    char* ws = (char*)d_ws;
    float2* V  = (float2*)ws;                          // 2 KB
    float* A   = (float*)(ws + 4096);                  // 12 MB region
    float* B   = (float*)(ws + 12587008);              // 8.5 MB region
    float* WT3 = (float*)(ws + 21499904);              // 128 KB
    float* WT4 = (float*)(ws + 21639168);              // 512 KB

    k_build_V<<<1, 256, 0, stream>>>(q_w, V);
    k_wtrans<<<640, 256, 0, stream>>>(conv3_w, conv4_w, WT3, WT4);
    k_cq<<<484, 256, 0, stream>>>(x, conv1_w, conv1_b, V, A);       // A: quanv 2 MB
    k_conv2p<<<256, 640, 0, stream>>>(A, conv2_w, conv2_b, B);      // B: pooled 8 MB
    k_conv3y<<<512, 448, 0, stream>>>(B, WT3, conv3_b, A);          // A: conv3 10.6 MB
    k_conv4y<<<512, 640, 0, stream>>>(A, WT4, B);                   // B: parts 6.6 MB
    k_fc1f<<<256, 256, 0, stream>>>(B, fc1_w, conv4_b, fc1_b, A);   // A: fc1 out
    k_fc_tail<<<256, 64, 0, stream>>>(A, fc2_w, fc2_b, fc3_w, fc3_b,
                                      fc4_w, fc4_b, out);
}